// Round 2
// baseline (710.693 us; speedup 1.0000x reference)
//
#include <hip/hip_runtime.h>
#include <hip/hip_bf16.h>
#include <stdint.h>

// Problem constants
#define L_   1280
#define B_   32
#define C_   256
#define H_   5
#define D_   256
#define BC_  8192            // B_*C_
#define EPSV 1e-5f

typedef __attribute__((ext_vector_type(8))) short bf16x8;   // 8 bf16 (4 VGPRs)
typedef __attribute__((ext_vector_type(4))) float f32x4;    // 4 fp32 acc
typedef __hip_bfloat16 bf16;

__device__ __forceinline__ bf16 f2bf(float v) { return __float2bfloat16(v); }

// ---------------------------------------------------------------------------
// Weight prep: fp32 [K,N] -> bf16 [N,K] (transposed) for 7 LxL matrices
// ---------------------------------------------------------------------------
struct WtArgs { const float* src[7]; bf16* dst[7]; };

__global__ __launch_bounds__(256) void transpose7(WtArgs a) {
    const int mat = blockIdx.z;
    const float* src = a.src[mat];
    bf16* dst = a.dst[mat];
    __shared__ float tile[32][33];
    const int bx = blockIdx.x * 32;   // n base
    const int by = blockIdx.y * 32;   // k base
    const int tx = threadIdx.x, ty = threadIdx.y;
    #pragma unroll
    for (int r = ty; r < 32; r += 8)
        tile[r][tx] = src[(size_t)(by + r) * L_ + bx + tx];
    __syncthreads();
    #pragma unroll
    for (int r = ty; r < 32; r += 8)
        dst[(size_t)(bx + r) * L_ + by + tx] = f2bf(tile[tx][r]);
}

// conv weight pack: conv_w[co][ci][t] -> WT[t][co][ci]; plus BN scale/bias
__global__ __launch_bounds__(256) void prep_conv(const float* cw, const float* g, const float* b,
                                                 const float* m, const float* v,
                                                 bf16* WT, float* sc, float* bi) {
    const int i = blockIdx.x * 256 + threadIdx.x;
    if (i < 3 * 256 * 256) {
        const int t = i >> 16;
        const int r = i & 65535;
        const int co = r >> 8, ci = r & 255;
        WT[i] = f2bf(cw[(co * 256 + ci) * 3 + t]);
    }
    if (i < 256) {
        const float s = g[i] * rsqrtf(v[i] + EPSV);
        sc[i] = s;
        bi[i] = b[i] - m[i] * s;
    }
}

// ---------------------------------------------------------------------------
// Rank kernel: rank[j] = (L - #{k: x[k] > x[j]}) / L   (eq-before term dropped;
// effect on node is < 2e-5, far below threshold). Bucket-histogram algorithm.
// ---------------------------------------------------------------------------
__global__ __launch_bounds__(256) void rank_kernel(const float* __restrict__ x, bf16* __restrict__ R) {
    __shared__ float vals[L_];
    __shared__ float sv[L_];
    __shared__ int hist[256];
    __shared__ int pfx[256];
    __shared__ int cur[256];
    const int row = blockIdx.x, tid = threadIdx.x;
    const float* src = x + (size_t)row * L_;
    for (int i = tid; i < L_; i += 256) vals[i] = src[i];
    hist[tid] = 0;
    __syncthreads();
    float myv[5]; int myb[5];
    #pragma unroll
    for (int ii = 0; ii < 5; ii++) {
        const float v = vals[tid + ii * 256];
        int bk = (int)((4.0f - v) * 32.0f);           // decreasing in v
        bk = bk < 0 ? 0 : (bk > 255 ? 255 : bk);
        myv[ii] = v; myb[ii] = bk;
        atomicAdd(&hist[bk], 1);
    }
    __syncthreads();
    pfx[tid] = hist[tid];
    __syncthreads();
    for (int off = 1; off < 256; off <<= 1) {         // inclusive scan
        int t = (tid >= off) ? pfx[tid - off] : 0;
        __syncthreads();
        pfx[tid] += t;
        __syncthreads();
    }
    cur[tid] = pfx[tid] - hist[tid];                  // exclusive base
    __syncthreads();
    #pragma unroll
    for (int ii = 0; ii < 5; ii++) {
        const int pos = atomicAdd(&cur[myb[ii]], 1);
        sv[pos] = myv[ii];
    }
    __syncthreads();
    #pragma unroll
    for (int ii = 0; ii < 5; ii++) {
        const int bk = myb[ii]; const float v = myv[ii];
        const int s = pfx[bk] - hist[bk], e = pfx[bk];
        int cg = s;                                   // all earlier buckets are strictly greater
        for (int p = s; p < e; p++) cg += (sv[p] > v) ? 1 : 0;
        R[(size_t)row * L_ + tid + ii * 256] = f2bf((float)(L_ - cg) * (1.0f / L_));
    }
}

// ---------------------------------------------------------------------------
// LayerNorm over last dim (1280), fp32 in -> bf16 out
// ---------------------------------------------------------------------------
__global__ __launch_bounds__(256) void ln_kernel(const float* __restrict__ in,
                                                 const float* __restrict__ g,
                                                 const float* __restrict__ b,
                                                 bf16* __restrict__ out) {
    const int row = blockIdx.x, tid = threadIdx.x;
    const float* src = in + (size_t)row * L_;
    float4 va = ((const float4*)src)[tid];
    float s = va.x + va.y + va.z + va.w;
    float ss = va.x * va.x + va.y * va.y + va.z * va.z + va.w * va.w;
    float4 vb = {0, 0, 0, 0};
    if (tid < 64) {
        vb = ((const float4*)src)[256 + tid];
        s += vb.x + vb.y + vb.z + vb.w;
        ss += vb.x * vb.x + vb.y * vb.y + vb.z * vb.z + vb.w * vb.w;
    }
    #pragma unroll
    for (int off = 32; off > 0; off >>= 1) {
        s += __shfl_down(s, off, 64);
        ss += __shfl_down(ss, off, 64);
    }
    __shared__ float rs[4], rss[4];
    __shared__ float mean_s, rstd_s;
    if ((tid & 63) == 0) { rs[tid >> 6] = s; rss[tid >> 6] = ss; }
    __syncthreads();
    if (tid == 0) {
        const float S = rs[0] + rs[1] + rs[2] + rs[3];
        const float SS = rss[0] + rss[1] + rss[2] + rss[3];
        const float m = S * (1.0f / L_);
        const float var = SS * (1.0f / L_) - m * m;
        mean_s = m; rstd_s = rsqrtf(var + EPSV);
    }
    __syncthreads();
    const float m = mean_s, r = rstd_s;
    {
        const int c = tid * 4;
        bf16 t4[4];
        t4[0] = f2bf((va.x - m) * r * g[c + 0] + b[c + 0]);
        t4[1] = f2bf((va.y - m) * r * g[c + 1] + b[c + 1]);
        t4[2] = f2bf((va.z - m) * r * g[c + 2] + b[c + 2]);
        t4[3] = f2bf((va.w - m) * r * g[c + 3] + b[c + 3]);
        *(uint2*)(out + (size_t)row * L_ + c) = *(uint2*)t4;
    }
    if (tid < 64) {
        const int c = 1024 + tid * 4;
        bf16 t4[4];
        t4[0] = f2bf((vb.x - m) * r * g[c + 0] + b[c + 0]);
        t4[1] = f2bf((vb.y - m) * r * g[c + 1] + b[c + 1]);
        t4[2] = f2bf((vb.z - m) * r * g[c + 2] + b[c + 2]);
        t4[3] = f2bf((vb.w - m) * r * g[c + 3] + b[c + 3]);
        *(uint2*)(out + (size_t)row * L_ + c) = *(uint2*)t4;
    }
}

// ---------------------------------------------------------------------------
// Row softmax: 256 fp32 -> 256 bf16, one wave per row (4 rows / block)
// ---------------------------------------------------------------------------
__global__ __launch_bounds__(256) void softmax_kernel(const float* __restrict__ S, bf16* __restrict__ P) {
    const int row = blockIdx.x * 4 + (threadIdx.x >> 6);
    const int l = threadIdx.x & 63;
    const float4 v = *(const float4*)(S + (size_t)row * 256 + l * 4);
    float mx = fmaxf(fmaxf(v.x, v.y), fmaxf(v.z, v.w));
    #pragma unroll
    for (int off = 1; off < 64; off <<= 1) mx = fmaxf(mx, __shfl_xor(mx, off, 64));
    const float e0 = expf(v.x - mx), e1 = expf(v.y - mx), e2 = expf(v.z - mx), e3 = expf(v.w - mx);
    float sm = e0 + e1 + e2 + e3;
    #pragma unroll
    for (int off = 1; off < 64; off <<= 1) sm += __shfl_xor(sm, off, 64);
    const float inv = 1.0f / sm;
    bf16 t4[4] = { f2bf(e0 * inv), f2bf(e1 * inv), f2bf(e2 * inv), f2bf(e3 * inv) };
    *(uint2*)(P + (size_t)row * 256 + l * 4) = *(uint2*)t4;
}

// zero the two pad rows of h2Tpad [B][1282][256]
__global__ __launch_bounds__(256) void zero_pads(bf16* h2T) {
    const int i = blockIdx.x * 256 + threadIdx.x;   // 32*2*256 = 16384
    const int b = i >> 9;
    const int which = (i >> 8) & 1;
    const int ci = i & 255;
    const long row = which ? 1281 : 0;
    h2T[(long)b * (1282 * 256) + row * 256 + ci] = f2bf(0.0f);
}

// ---------------------------------------------------------------------------
// Generic batched GEMM: C[z][m][n] = sum_k A[z][m][k] * Bt[z][n][k]
// 128x128 tile, BK=32, 4 waves, mfma_f32_16x16x32_bf16, reg-staged LDS.
// z decomposed as zq = z / zmod, zr = z % zmod; offsets = zq*s1 + zr*s2.
// ---------------------------------------------------------------------------
struct GemmP {
    const bf16* A;  long lda, sA1, sA2;
    const bf16* Bt; long ldb, sB1, sB2;
    int zmod;
    int K;
    float* outF; bf16* outB; long ldc, sC1, sC2;
    const float* bias;
    const float* res; long ldres, sR1, sR2;
    const float* rowscale; const float* rowbias;
    float scale;
};

constexpr int E_F32_BIAS_RES = 0;  // outF = acc + bias[col] + res  (outF may == res, same-index)
constexpr int E_BF16_BIAS = 1;     // outB = bf16(acc + bias[col])
constexpr int E_BF16_BIAS_SCALE = 2;
constexpr int E_VT = 3;            // v-transpose store [b,h,d,c]
constexpr int E_F32 = 4;           // outF = acc       (with z offset)
constexpr int E_BF16 = 5;          // outB = bf16(acc) (with z offset)
constexpr int E_GELU = 6;          // outB = bf16(gelu(acc+bias))
constexpr int E_FFN2T = 7;         // h2 transposed+padded store
constexpr int E_ACC = 8;           // outF += acc
constexpr int E_CONVFIN = 9;       // relu((res+acc)*rowscale+rowbias) -> outF

template <int EPI>
__global__ __launch_bounds__(256) void gemm_bt(GemmP p) {
    const int z = blockIdx.z;
    const int zq = z / p.zmod, zr = z % p.zmod;
    const bf16* A  = p.A  + (long)zq * p.sA1 + (long)zr * p.sA2;
    const bf16* Bt = p.Bt + (long)zq * p.sB1 + (long)zr * p.sB2;
    const int row0 = blockIdx.y * 128, col0 = blockIdx.x * 128;

    __shared__ __align__(16) bf16 ldsA[128 * 32];
    __shared__ __align__(16) bf16 ldsB[128 * 32];

    const int tid = threadIdx.x;
    const int l = tid & 63, w = tid >> 6;
    const int wr = w >> 1, wc = w & 1;

    f32x4 acc[4][4];
    #pragma unroll
    for (int m = 0; m < 4; m++)
        #pragma unroll
        for (int n = 0; n < 4; n++)
            acc[m][n] = (f32x4){0.f, 0.f, 0.f, 0.f};

    const bf16* gA = A  + (long)(row0 + w * 16 + (l >> 2)) * p.lda + (l & 3) * 8;
    const bf16* gB = Bt + (long)(col0 + w * 16 + (l >> 2)) * p.ldb + (l & 3) * 8;
    const long aStep = 64 * p.lda, bStep = 64 * p.ldb;

    for (int kt = 0; kt < p.K; kt += 32) {
        const uint4 ra0 = *(const uint4*)gA;
        const uint4 ra1 = *(const uint4*)(gA + aStep);
        const uint4 rb0 = *(const uint4*)gB;
        const uint4 rb1 = *(const uint4*)(gB + bStep);
        gA += 32; gB += 32;
        *(uint4*)(ldsA + w * 512 + l * 8)        = ra0;
        *(uint4*)(ldsA + 2048 + w * 512 + l * 8) = ra1;
        *(uint4*)(ldsB + w * 512 + l * 8)        = rb0;
        *(uint4*)(ldsB + 2048 + w * 512 + l * 8) = rb1;
        __syncthreads();
        bf16x8 aF[4], bF[4];
        #pragma unroll
        for (int m = 0; m < 4; m++)
            aF[m] = *(const bf16x8*)(ldsA + (wr * 64 + m * 16 + (l & 15)) * 32 + (l >> 4) * 8);
        #pragma unroll
        for (int n = 0; n < 4; n++)
            bF[n] = *(const bf16x8*)(ldsB + (wc * 64 + n * 16 + (l & 15)) * 32 + (l >> 4) * 8);
        #pragma unroll
        for (int m = 0; m < 4; m++)
            #pragma unroll
            for (int n = 0; n < 4; n++)
                acc[m][n] = __builtin_amdgcn_mfma_f32_16x16x32_bf16(aF[m], bF[n], acc[m][n], 0, 0, 0);
        __syncthreads();
    }

    const long cz = (long)zq * p.sC1 + (long)zr * p.sC2;
    const long rz = (long)zq * p.sR1 + (long)zr * p.sR2;
    #pragma unroll
    for (int m = 0; m < 4; m++) {
        #pragma unroll
        for (int n = 0; n < 4; n++) {
            const int gcol = col0 + wc * 64 + n * 16 + (l & 15);
            #pragma unroll
            for (int j = 0; j < 4; j++) {
                const int grow = row0 + wr * 64 + m * 16 + (l >> 4) * 4 + j;
                const float v = acc[m][n][j];
                if constexpr (EPI == E_F32_BIAS_RES) {
                    p.outF[cz + (long)grow * p.ldc + gcol] =
                        v + p.bias[gcol] + p.res[rz + (long)grow * p.ldres + gcol];
                } else if constexpr (EPI == E_BF16_BIAS) {
                    p.outB[cz + (long)grow * p.ldc + gcol] = f2bf(v + p.bias[gcol]);
                } else if constexpr (EPI == E_BF16_BIAS_SCALE) {
                    p.outB[cz + (long)grow * p.ldc + gcol] = f2bf((v + p.bias[gcol]) * p.scale);
                } else if constexpr (EPI == E_VT) {
                    const int b_ = grow >> 8, c_ = grow & 255;
                    const int h_ = gcol >> 8, d_ = gcol & 255;
                    p.outB[(((long)(b_ * H_ + h_) * 256 + d_) << 8) + c_] = f2bf(v + p.bias[gcol]);
                } else if constexpr (EPI == E_F32) {
                    p.outF[cz + (long)grow * p.ldc + gcol] = v;
                } else if constexpr (EPI == E_BF16) {
                    p.outB[cz + (long)grow * p.ldc + gcol] = f2bf(v);
                } else if constexpr (EPI == E_GELU) {
                    const float t = v + p.bias[gcol];
                    p.outB[cz + (long)grow * p.ldc + gcol] =
                        f2bf(0.5f * t * (1.0f + erff(t * 0.70710678f)));
                } else if constexpr (EPI == E_FFN2T) {
                    const float t = v + p.bias[gcol] + p.res[rz + (long)grow * p.ldres + gcol];
                    const int b_ = grow >> 8, ci = grow & 255;
                    p.outB[(long)b_ * (1282 * 256) + (long)(gcol + 1) * 256 + ci] = f2bf(t);
                } else if constexpr (EPI == E_ACC) {
                    p.outF[cz + (long)grow * p.ldc + gcol] += v;
                } else if constexpr (EPI == E_CONVFIN) {
                    float t = p.res[rz + (long)grow * p.ldres + gcol] + v;
                    t = t * p.rowscale[grow] + p.rowbias[grow];
                    p.outF[cz + (long)grow * p.ldc + gcol] = fmaxf(t, 0.0f);
                }
            }
        }
    }
}

// ---------------------------------------------------------------------------
extern "C" void kernel_launch(void* const* d_in, const int* in_sizes, int n_in,
                              void* d_out, int out_size, void* d_ws, size_t ws_size,
                              hipStream_t stream) {
    const float* x    = (const float*)d_in[0];
    const float* re_w = (const float*)d_in[1];
    const float* re_b = (const float*)d_in[2];
    const float* ln1g = (const float*)d_in[3];
    const float* ln1b = (const float*)d_in[4];
    const float* ln2g = (const float*)d_in[5];
    const float* ln2b = (const float*)d_in[6];
    const float* wq   = (const float*)d_in[7];
    const float* bq   = (const float*)d_in[8];
    const float* wk   = (const float*)d_in[9];
    const float* bk   = (const float*)d_in[10];
    const float* wv   = (const float*)d_in[11];
    const float* bv   = (const float*)d_in[12];
    const float* wo   = (const float*)d_in[13];
    const float* bo   = (const float*)d_in[14];
    const float* fw1  = (const float*)d_in[15];
    const float* fb1  = (const float*)d_in[16];
    const float* fw2  = (const float*)d_in[17];
    const float* fb2  = (const float*)d_in[18];
    const float* convw = (const float*)d_in[19];
    const float* bng  = (const float*)d_in[20];
    const float* bnb  = (const float*)d_in[21];
    const float* bnm  = (const float*)d_in[22];
    const float* bnv  = (const float*)d_in[23];
    float* out = (float*)d_out;

    // ---- workspace layout (total 191,137,792 bytes) ----
    char* ws = (char*)d_ws;
    const size_t SZ_WT     = (size_t)L_ * L_ * 2;          // 3,276,800
    const size_t SZ_ACT_BF = (size_t)BC_ * L_ * 2;         // 20,971,520
    const size_t SZ_ACT_F  = (size_t)BC_ * L_ * 4;         // 41,943,040
    const size_t SZ_H2T    = (size_t)B_ * 1282 * 256 * 2;  // 21,004,288
    const size_t SZ_S      = (size_t)160 * 256 * 256 * 4;  // 41,943,040

    size_t off = 0;
    bf16* Wt[7];
    for (int i = 0; i < 7; i++) { Wt[i] = (bf16*)(ws + off); off += SZ_WT; }
    bf16* WconvT   = (bf16*)(ws + off); off += 393216;
    float* bnscale = (float*)(ws + off); off += 1024;
    float* bnbias  = (float*)(ws + off); off += 1024;
    bf16* RP  = (bf16*)(ws + off); off += SZ_ACT_BF;  // rank -> P -> y2
    bf16* Yb  = (bf16*)(ws + off); off += SZ_ACT_BF;  // y -> f1
    bf16* Qb  = (bf16*)(ws + off); off += SZ_ACT_BF;  // q -> attn O
    bf16* Kb  = (bf16*)(ws + off); off += SZ_H2T;     // k -> h2Tpad
    float* Sb = (float*)(ws + off); off += SZ_S;      // scores -> V^T -> convsum
    float* node = (float*)(ws + off); off += SZ_ACT_F; // node -> h (in place)
    bf16* VT = (bf16*)Sb;                              // V^T aliases score buffer
    (void)in_sizes; (void)n_in; (void)out_size;

    // Diagnostic guard: if ws is too small, fail cleanly (absmax ~8.5, no fault)
    if (ws_size < off) return;

    // ---- weight prep ----
    WtArgs wa;
    wa.src[0] = re_w; wa.src[1] = wq; wa.src[2] = wk; wa.src[3] = wv;
    wa.src[4] = wo;  wa.src[5] = fw1; wa.src[6] = fw2;
    for (int i = 0; i < 7; i++) wa.dst[i] = Wt[i];
    transpose7<<<dim3(40, 40, 7), dim3(32, 8), 0, stream>>>(wa);
    prep_conv<<<dim3(768), 256, 0, stream>>>(convw, bng, bnb, bnm, bnv, WconvT, bnscale, bnbias);

    // ---- rank ----
    rank_kernel<<<dim3(BC_), 256, 0, stream>>>(x, RP);

    const dim3 gBig(L_ / 128, BC_ / 128, 1);      // (10, 64)
    const dim3 gAttn(2, 2, 160);
    const dim3 blk(256);

    // ---- node = x + rank @ re_w + re_b (fp32) ----
    {
        GemmP p{}; p.zmod = 1; p.K = L_;
        p.A = RP; p.lda = L_; p.Bt = Wt[0]; p.ldb = L_;
        p.outF = node; p.ldc = L_; p.bias = re_b; p.res = x; p.ldres = L_;
        gemm_bt<E_F32_BIAS_RES><<<gBig, blk, 0, stream>>>(p);
    }
    // ---- LN1 -> y ----
    ln_kernel<<<dim3(BC_), blk, 0, stream>>>(node, ln1g, ln1b, Yb);
    // ---- Q (scaled), K ----
    {
        GemmP p{}; p.zmod = 1; p.K = L_;
        p.A = Yb; p.lda = L_; p.Bt = Wt[1]; p.ldb = L_;
        p.outB = Qb; p.ldc = L_; p.bias = bq; p.scale = 0.0625f;  // D^-0.5
        gemm_bt<E_BF16_BIAS_SCALE><<<gBig, blk, 0, stream>>>(p);
    }
    {
        GemmP p{}; p.zmod = 1; p.K = L_;
        p.A = Yb; p.lda = L_; p.Bt = Wt[2]; p.ldb = L_;
        p.outB = Kb; p.ldc = L_; p.bias = bk;
        gemm_bt<E_BF16_BIAS><<<gBig, blk, 0, stream>>>(p);
    }
    // ---- S = q k^T per (b,h) ----
    {
        GemmP p{}; p.zmod = H_; p.K = 256;
        p.A = Qb;  p.lda = L_; p.sA1 = (long)C_ * L_; p.sA2 = 256;
        p.Bt = Kb; p.ldb = L_; p.sB1 = (long)C_ * L_; p.sB2 = 256;
        p.outF = Sb; p.ldc = 256; p.sC1 = (long)H_ * 65536; p.sC2 = 65536;
        gemm_bt<E_F32><<<gAttn, blk, 0, stream>>>(p);
    }
    // ---- softmax -> P (into RP; rank is dead) ----
    softmax_kernel<<<dim3(160 * 256 / 4), blk, 0, stream>>>(Sb, RP);
    // ---- V (transposed, into VT = Sb region; scores are dead) ----
    {
        GemmP p{}; p.zmod = 1; p.K = L_;
        p.A = Yb; p.lda = L_; p.Bt = Wt[3]; p.ldb = L_;
        p.outB = VT; p.bias = bv;
        gemm_bt<E_VT><<<gBig, blk, 0, stream>>>(p);
    }
    // ---- O = P V  (into Qb; q is dead) ----
    {
        GemmP p{}; p.zmod = H_; p.K = 256;
        p.A = RP;  p.lda = 256; p.sA1 = (long)H_ * 65536; p.sA2 = 65536;
        p.Bt = VT; p.ldb = 256; p.sB1 = (long)H_ * 65536; p.sB2 = 65536;
        p.outB = Qb; p.ldc = L_; p.sC1 = (long)C_ * L_; p.sC2 = 256;
        gemm_bt<E_BF16><<<gAttn, blk, 0, stream>>>(p);
    }
    // ---- h = node + O @ wo + bo (fp32, in place over node) ----
    {
        GemmP p{}; p.zmod = 1; p.K = L_;
        p.A = Qb; p.lda = L_; p.Bt = Wt[4]; p.ldb = L_;
        p.outF = node; p.ldc = L_; p.bias = bo; p.res = node; p.ldres = L_;
        gemm_bt<E_F32_BIAS_RES><<<gBig, blk, 0, stream>>>(p);
    }
    // ---- LN2 -> y2 (RP; P is dead) ----
    ln_kernel<<<dim3(BC_), blk, 0, stream>>>(node, ln2g, ln2b, RP);
    // ---- f1 = gelu(y2 @ w1 + b1) (Yb; y is dead) ----
    {
        GemmP p{}; p.zmod = 1; p.K = L_;
        p.A = RP; p.lda = L_; p.Bt = Wt[5]; p.ldb = L_;
        p.outB = Yb; p.ldc = L_; p.bias = fb1;
        gemm_bt<E_GELU><<<gBig, blk, 0, stream>>>(p);
    }
    // ---- h2 = h + f1 @ w2 + b2 -> transposed+padded (Kb; k is dead) ----
    zero_pads<<<dim3(64), blk, 0, stream>>>(Kb);
    {
        GemmP p{}; p.zmod = 1; p.K = L_;
        p.A = Yb; p.lda = L_; p.Bt = Wt[6]; p.ldb = L_;
        p.outB = Kb; p.bias = fb2; p.res = node; p.ldres = L_;
        gemm_bt<E_FFN2T><<<gBig, blk, 0, stream>>>(p);
    }
    // ---- conv as 3 shifted GEMMs + BN + ReLU (convsum in Sb; VT dead) ----
    const dim3 gConv(L_ / 128, 2, B_);
    {   // tap 0: write
        GemmP p{}; p.zmod = 1; p.K = 256;
        p.A = WconvT; p.lda = 256;
        p.Bt = Kb; p.ldb = 256; p.sB1 = 1282 * 256;
        p.outF = Sb; p.ldc = L_; p.sC1 = (long)C_ * L_;
        gemm_bt<E_F32><<<gConv, blk, 0, stream>>>(p);
    }
    {   // tap 1: accumulate
        GemmP p{}; p.zmod = 1; p.K = 256;
        p.A = WconvT + 65536; p.lda = 256;
        p.Bt = Kb + 256; p.ldb = 256; p.sB1 = 1282 * 256;
        p.outF = Sb; p.ldc = L_; p.sC1 = (long)C_ * L_;
        gemm_bt<E_ACC><<<gConv, blk, 0, stream>>>(p);
    }
    {   // tap 2: finish + BN + ReLU -> d_out
        GemmP p{}; p.zmod = 1; p.K = 256;
        p.A = WconvT + 2 * 65536; p.lda = 256;
        p.Bt = Kb + 2 * 256; p.ldb = 256; p.sB1 = 1282 * 256;
        p.res = Sb; p.ldres = L_; p.sR1 = (long)C_ * L_;
        p.outF = out; p.ldc = L_; p.sC1 = (long)C_ * L_;
        p.rowscale = bnscale; p.rowbias = bnbias;
        gemm_bt<E_CONVFIN><<<gConv, blk, 0, stream>>>(p);
    }
}

// Round 6
// 650.679 us; speedup vs baseline: 1.0922x; 1.0922x over previous
//
#include <hip/hip_runtime.h>
#include <hip/hip_bf16.h>
#include <stdint.h>

// Problem constants
#define L_   1280
#define B_   32
#define C_   256
#define H_   5
#define D_   256
#define BC_  8192            // B_*C_
#define EPSV 1e-5f

typedef __attribute__((ext_vector_type(8))) short bf16x8;   // 8 bf16 (4 VGPRs)
typedef __attribute__((ext_vector_type(4))) float f32x4;    // 4 fp32 acc
typedef __hip_bfloat16 bf16;

__device__ __forceinline__ bf16 f2bf(float v) { return __float2bfloat16(v); }

// async global->LDS, 16B per lane; LDS dest is wave-uniform base + lane*16
#define GLDS16(gptr, lptr)                                                        \
    __builtin_amdgcn_global_load_lds(                                             \
        (const __attribute__((address_space(1))) void*)(gptr),                    \
        (__attribute__((address_space(3))) void*)(lptr), 16, 0, 0)

// ---------------------------------------------------------------------------
// Weight prep: fp32 [K,N] -> bf16 [N,K] (transposed) for 7 LxL matrices
// ---------------------------------------------------------------------------
struct WtArgs { const float* src[7]; bf16* dst[7]; };

__global__ __launch_bounds__(256) void transpose7(WtArgs a) {
    const int mat = blockIdx.z;
    const float* src = a.src[mat];
    bf16* dst = a.dst[mat];
    __shared__ float tile[32][33];
    const int bx = blockIdx.x * 32;   // n base
    const int by = blockIdx.y * 32;   // k base
    const int tx = threadIdx.x, ty = threadIdx.y;
    #pragma unroll
    for (int r = ty; r < 32; r += 8)
        tile[r][tx] = src[(size_t)(by + r) * L_ + bx + tx];
    __syncthreads();
    #pragma unroll
    for (int r = ty; r < 32; r += 8)
        dst[(size_t)(bx + r) * L_ + by + tx] = f2bf(tile[tx][r]);
}

// conv weight pack: conv_w[co][ci][t] -> WT[co][t*256+ci]  (K=768 fused layout)
// plus BN scale/bias
__global__ __launch_bounds__(256) void prep_conv(const float* cw, const float* g, const float* b,
                                                 const float* m, const float* v,
                                                 bf16* WT, float* sc, float* bi) {
    const int i = blockIdx.x * 256 + threadIdx.x;
    if (i < 3 * 256 * 256) {
        const int co = i / 768;
        const int r = i - co * 768;
        const int t = r >> 8, ci = r & 255;
        WT[i] = f2bf(cw[(co * 256 + ci) * 3 + t]);
    }
    if (i < 256) {
        const float s = g[i] * rsqrtf(v[i] + EPSV);
        sc[i] = s;
        bi[i] = b[i] - m[i] * s;
    }
}

// ---------------------------------------------------------------------------
// Rank kernel: rank[j] = (L - #{k: x[k] > x[j]}) / L   (eq-before term dropped;
// effect on node is < 2e-5, far below threshold). Bucket-histogram algorithm.
// ---------------------------------------------------------------------------
__global__ __launch_bounds__(256) void rank_kernel(const float* __restrict__ x, bf16* __restrict__ R) {
    __shared__ float vals[L_];
    __shared__ float sv[L_];
    __shared__ int hist[256];
    __shared__ int pfx[256];
    __shared__ int cur[256];
    const int row = blockIdx.x, tid = threadIdx.x;
    const float* src = x + (size_t)row * L_;
    for (int i = tid; i < L_; i += 256) vals[i] = src[i];
    hist[tid] = 0;
    __syncthreads();
    float myv[5]; int myb[5];
    #pragma unroll
    for (int ii = 0; ii < 5; ii++) {
        const float v = vals[tid + ii * 256];
        int bk = (int)((4.0f - v) * 32.0f);           // decreasing in v
        bk = bk < 0 ? 0 : (bk > 255 ? 255 : bk);
        myv[ii] = v; myb[ii] = bk;
        atomicAdd(&hist[bk], 1);
    }
    __syncthreads();
    pfx[tid] = hist[tid];
    __syncthreads();
    for (int off = 1; off < 256; off <<= 1) {         // inclusive scan
        int t = (tid >= off) ? pfx[tid - off] : 0;
        __syncthreads();
        pfx[tid] += t;
        __syncthreads();
    }
    cur[tid] = pfx[tid] - hist[tid];                  // exclusive base
    __syncthreads();
    #pragma unroll
    for (int ii = 0; ii < 5; ii++) {
        const int pos = atomicAdd(&cur[myb[ii]], 1);
        sv[pos] = myv[ii];
    }
    __syncthreads();
    #pragma unroll
    for (int ii = 0; ii < 5; ii++) {
        const int bk = myb[ii]; const float v = myv[ii];
        const int s = pfx[bk] - hist[bk], e = pfx[bk];
        int cg = s;                                   // all earlier buckets are strictly greater
        for (int p = s; p < e; p++) cg += (sv[p] > v) ? 1 : 0;
        R[(size_t)row * L_ + tid + ii * 256] = f2bf((float)(L_ - cg) * (1.0f / L_));
    }
}

// ---------------------------------------------------------------------------
// LayerNorm over last dim (1280), fp32 in -> bf16 out
// ---------------------------------------------------------------------------
__global__ __launch_bounds__(256) void ln_kernel(const float* __restrict__ in,
                                                 const float* __restrict__ g,
                                                 const float* __restrict__ b,
                                                 bf16* __restrict__ out) {
    const int row = blockIdx.x, tid = threadIdx.x;
    const float* src = in + (size_t)row * L_;
    float4 va = ((const float4*)src)[tid];
    float s = va.x + va.y + va.z + va.w;
    float ss = va.x * va.x + va.y * va.y + va.z * va.z + va.w * va.w;
    float4 vb = {0, 0, 0, 0};
    if (tid < 64) {
        vb = ((const float4*)src)[256 + tid];
        s += vb.x + vb.y + vb.z + vb.w;
        ss += vb.x * vb.x + vb.y * vb.y + vb.z * vb.z + vb.w * vb.w;
    }
    #pragma unroll
    for (int off = 32; off > 0; off >>= 1) {
        s += __shfl_down(s, off, 64);
        ss += __shfl_down(ss, off, 64);
    }
    __shared__ float rs[4], rss[4];
    __shared__ float mean_s, rstd_s;
    if ((tid & 63) == 0) { rs[tid >> 6] = s; rss[tid >> 6] = ss; }
    __syncthreads();
    if (tid == 0) {
        const float S = rs[0] + rs[1] + rs[2] + rs[3];
        const float SS = rss[0] + rss[1] + rss[2] + rss[3];
        const float m = S * (1.0f / L_);
        const float var = SS * (1.0f / L_) - m * m;
        mean_s = m; rstd_s = rsqrtf(var + EPSV);
    }
    __syncthreads();
    const float m = mean_s, r = rstd_s;
    {
        const int c = tid * 4;
        bf16 t4[4];
        t4[0] = f2bf((va.x - m) * r * g[c + 0] + b[c + 0]);
        t4[1] = f2bf((va.y - m) * r * g[c + 1] + b[c + 1]);
        t4[2] = f2bf((va.z - m) * r * g[c + 2] + b[c + 2]);
        t4[3] = f2bf((va.w - m) * r * g[c + 3] + b[c + 3]);
        *(uint2*)(out + (size_t)row * L_ + c) = *(uint2*)t4;
    }
    if (tid < 64) {
        const int c = 1024 + tid * 4;
        bf16 t4[4];
        t4[0] = f2bf((vb.x - m) * r * g[c + 0] + b[c + 0]);
        t4[1] = f2bf((vb.y - m) * r * g[c + 1] + b[c + 1]);
        t4[2] = f2bf((vb.z - m) * r * g[c + 2] + b[c + 2]);
        t4[3] = f2bf((vb.w - m) * r * g[c + 3] + b[c + 3]);
        *(uint2*)(out + (size_t)row * L_ + c) = *(uint2*)t4;
    }
}

// ---------------------------------------------------------------------------
// Row softmax: 256 fp32 -> 256 bf16, one wave per row (4 rows / block)
// ---------------------------------------------------------------------------
__global__ __launch_bounds__(256) void softmax_kernel(const float* __restrict__ S, bf16* __restrict__ P) {
    const int row = blockIdx.x * 4 + (threadIdx.x >> 6);
    const int l = threadIdx.x & 63;
    const float4 v = *(const float4*)(S + (size_t)row * 256 + l * 4);
    float mx = fmaxf(fmaxf(v.x, v.y), fmaxf(v.z, v.w));
    #pragma unroll
    for (int off = 1; off < 64; off <<= 1) mx = fmaxf(mx, __shfl_xor(mx, off, 64));
    const float e0 = expf(v.x - mx), e1 = expf(v.y - mx), e2 = expf(v.z - mx), e3 = expf(v.w - mx);
    float sm = e0 + e1 + e2 + e3;
    #pragma unroll
    for (int off = 1; off < 64; off <<= 1) sm += __shfl_xor(sm, off, 64);
    const float inv = 1.0f / sm;
    bf16 t4[4] = { f2bf(e0 * inv), f2bf(e1 * inv), f2bf(e2 * inv), f2bf(e3 * inv) };
    *(uint2*)(P + (size_t)row * 256 + l * 4) = *(uint2*)t4;
}

// zero the two pad rows of h2Tpad [B][1282][256]
__global__ __launch_bounds__(256) void zero_pads(bf16* h2T) {
    const int i = blockIdx.x * 256 + threadIdx.x;   // 32*2*256 = 16384
    const int b = i >> 9;
    const int which = (i >> 8) & 1;
    const int ci = i & 255;
    const long row = which ? 1281 : 0;
    h2T[(long)b * (1282 * 256) + row * 256 + ci] = f2bf(0.0f);
}

// ---------------------------------------------------------------------------
// Generic batched GEMM: C[z][m][n] = sum_k A[z][m][k] * Bt[z][n][k]
// 128x128 tile, BK=32, 4 waves, mfma_f32_16x16x32_bf16.
// Staging via global_load_lds width=16 (wave-uniform LDS dest + lane*16B).
// z decomposed as zq = z / zmod, zr = z % zmod; offsets = zq*s1 + zr*s2.
// ---------------------------------------------------------------------------
struct GemmP {
    const bf16* A;  long lda, sA1, sA2;
    const bf16* Bt; long ldb, sB1, sB2;
    int zmod;
    int K;
    float* outF; bf16* outB; long ldc, sC1, sC2;
    const float* bias;
    const float* res; long ldres, sR1, sR2;
    const float* rowscale; const float* rowbias;
    float scale;
};

constexpr int E_F32_BIAS_RES = 0;  // outF = acc + bias[col] + res  (outF may == res, same-index)
constexpr int E_BF16_BIAS = 1;     // outB = bf16(acc + bias[col])
constexpr int E_BF16_BIAS_SCALE = 2;
constexpr int E_VT = 3;            // v-transpose store [b,h,d,c]
constexpr int E_F32 = 4;           // outF = acc       (with z offset)
constexpr int E_BF16 = 5;          // outB = bf16(acc) (with z offset)
constexpr int E_GELU = 6;          // outB = bf16(gelu(acc+bias))
constexpr int E_FFN2T = 7;         // h2 transposed+padded store
constexpr int E_CONVBNR = 8;       // relu(acc*rowscale+rowbias) -> outF

template <int EPI>
__global__ __launch_bounds__(256) void gemm_bt(GemmP p) {
    const int z = blockIdx.z;
    const int zq = z / p.zmod, zr = z % p.zmod;
    const bf16* A  = p.A  + (long)zq * p.sA1 + (long)zr * p.sA2;
    const bf16* Bt = p.Bt + (long)zq * p.sB1 + (long)zr * p.sB2;
    const int row0 = blockIdx.y * 128, col0 = blockIdx.x * 128;

    __shared__ __align__(16) bf16 ldsA[128 * 32];
    __shared__ __align__(16) bf16 ldsB[128 * 32];

    const int tid = threadIdx.x;
    const int l = tid & 63, w = tid >> 6;
    const int wr = w >> 1, wc = w & 1;

    f32x4 acc[4][4];
    #pragma unroll
    for (int m = 0; m < 4; m++)
        #pragma unroll
        for (int n = 0; n < 4; n++)
            acc[m][n] = (f32x4){0.f, 0.f, 0.f, 0.f};

    const bf16* gA = A  + (long)(row0 + w * 16 + (l >> 2)) * p.lda + (l & 3) * 8;
    const bf16* gB = Bt + (long)(col0 + w * 16 + (l >> 2)) * p.ldb + (l & 3) * 8;
    const long aStep = 64 * p.lda, bStep = 64 * p.ldb;

    // wave-uniform LDS bases (HW adds lane*16B)
    bf16* const lA0 = ldsA + w * 512;
    bf16* const lA1 = ldsA + 2048 + w * 512;
    bf16* const lB0 = ldsB + w * 512;
    bf16* const lB1 = ldsB + 2048 + w * 512;

    for (int kt = 0; kt < p.K; kt += 32) {
        GLDS16(gA,         lA0);
        GLDS16(gA + aStep, lA1);
        GLDS16(gB,         lB0);
        GLDS16(gB + bStep, lB1);
        gA += 32; gB += 32;
        __syncthreads();
        bf16x8 aF[4], bF[4];
        #pragma unroll
        for (int m = 0; m < 4; m++)
            aF[m] = *(const bf16x8*)(ldsA + (wr * 64 + m * 16 + (l & 15)) * 32 + (l >> 4) * 8);
        #pragma unroll
        for (int n = 0; n < 4; n++)
            bF[n] = *(const bf16x8*)(ldsB + (wc * 64 + n * 16 + (l & 15)) * 32 + (l >> 4) * 8);
        #pragma unroll
        for (int m = 0; m < 4; m++)
            #pragma unroll
            for (int n = 0; n < 4; n++)
                acc[m][n] = __builtin_amdgcn_mfma_f32_16x16x32_bf16(aF[m], bF[n], acc[m][n], 0, 0, 0);
        __syncthreads();
    }

    const long cz = (long)zq * p.sC1 + (long)zr * p.sC2;
    const long rz = (long)zq * p.sR1 + (long)zr * p.sR2;
    #pragma unroll
    for (int m = 0; m < 4; m++) {
        #pragma unroll
        for (int n = 0; n < 4; n++) {
            const int gcol = col0 + wc * 64 + n * 16 + (l & 15);
            #pragma unroll
            for (int j = 0; j < 4; j++) {
                const int grow = row0 + wr * 64 + m * 16 + (l >> 4) * 4 + j;
                const float v = acc[m][n][j];
                if constexpr (EPI == E_F32_BIAS_RES) {
                    p.outF[cz + (long)grow * p.ldc + gcol] =
                        v + p.bias[gcol] + p.res[rz + (long)grow * p.ldres + gcol];
                } else if constexpr (EPI == E_BF16_BIAS) {
                    p.outB[cz + (long)grow * p.ldc + gcol] = f2bf(v + p.bias[gcol]);
                } else if constexpr (EPI == E_BF16_BIAS_SCALE) {
                    p.outB[cz + (long)grow * p.ldc + gcol] = f2bf((v + p.bias[gcol]) * p.scale);
                } else if constexpr (EPI == E_VT) {
                    const int b_ = grow >> 8, c_ = grow & 255;
                    const int h_ = gcol >> 8, d_ = gcol & 255;
                    p.outB[(((long)(b_ * H_ + h_) * 256 + d_) << 8) + c_] = f2bf(v + p.bias[gcol]);
                } else if constexpr (EPI == E_F32) {
                    p.outF[cz + (long)grow * p.ldc + gcol] = v;
                } else if constexpr (EPI == E_BF16) {
                    p.outB[cz + (long)grow * p.ldc + gcol] = f2bf(v);
                } else if constexpr (EPI == E_GELU) {
                    const float t = v + p.bias[gcol];
                    p.outB[cz + (long)grow * p.ldc + gcol] =
                        f2bf(0.5f * t * (1.0f + erff(t * 0.70710678f)));
                } else if constexpr (EPI == E_FFN2T) {
                    const float t = v + p.bias[gcol] + p.res[rz + (long)grow * p.ldres + gcol];
                    const int b_ = grow >> 8, ci = grow & 255;
                    p.outB[(long)b_ * (1282 * 256) + (long)(gcol + 1) * 256 + ci] = f2bf(t);
                } else if constexpr (EPI == E_CONVBNR) {
                    const float t = v * p.rowscale[grow] + p.rowbias[grow];
                    p.outF[cz + (long)grow * p.ldc + gcol] = fmaxf(t, 0.0f);
                }
            }
        }
    }
}

// ---------------------------------------------------------------------------
extern "C" void kernel_launch(void* const* d_in, const int* in_sizes, int n_in,
                              void* d_out, int out_size, void* d_ws, size_t ws_size,
                              hipStream_t stream) {
    const float* x    = (const float*)d_in[0];
    const float* re_w = (const float*)d_in[1];
    const float* re_b = (const float*)d_in[2];
    const float* ln1g = (const float*)d_in[3];
    const float* ln1b = (const float*)d_in[4];
    const float* ln2g = (const float*)d_in[5];
    const float* ln2b = (const float*)d_in[6];
    const float* wq   = (const float*)d_in[7];
    const float* bq   = (const float*)d_in[8];
    const float* wk   = (const float*)d_in[9];
    const float* bk   = (const float*)d_in[10];
    const float* wv   = (const float*)d_in[11];
    const float* bv   = (const float*)d_in[12];
    const float* wo   = (const float*)d_in[13];
    const float* bo   = (const float*)d_in[14];
    const float* fw1  = (const float*)d_in[15];
    const float* fb1  = (const float*)d_in[16];
    const float* fw2  = (const float*)d_in[17];
    const float* fb2  = (const float*)d_in[18];
    const float* convw = (const float*)d_in[19];
    const float* bng  = (const float*)d_in[20];
    const float* bnb  = (const float*)d_in[21];
    const float* bnm  = (const float*)d_in[22];
    const float* bnv  = (const float*)d_in[23];
    float* out = (float*)d_out;

    // ---- workspace layout (total 191,137,792 bytes) ----
    char* ws = (char*)d_ws;
    const size_t SZ_WT     = (size_t)L_ * L_ * 2;          // 3,276,800
    const size_t SZ_ACT_BF = (size_t)BC_ * L_ * 2;         // 20,971,520
    const size_t SZ_ACT_F  = (size_t)BC_ * L_ * 4;         // 41,943,040
    const size_t SZ_H2T    = (size_t)B_ * 1282 * 256 * 2;  // 21,004,288
    const size_t SZ_S      = (size_t)160 * 256 * 256 * 4;  // 41,943,040

    size_t off = 0;
    bf16* Wt[7];
    for (int i = 0; i < 7; i++) { Wt[i] = (bf16*)(ws + off); off += SZ_WT; }
    bf16* WconvT   = (bf16*)(ws + off); off += 393216;
    float* bnscale = (float*)(ws + off); off += 1024;
    float* bnbias  = (float*)(ws + off); off += 1024;
    bf16* RP  = (bf16*)(ws + off); off += SZ_ACT_BF;  // rank -> P -> y2
    bf16* Yb  = (bf16*)(ws + off); off += SZ_ACT_BF;  // y -> f1
    bf16* Qb  = (bf16*)(ws + off); off += SZ_ACT_BF;  // q -> attn O
    bf16* Kb  = (bf16*)(ws + off); off += SZ_H2T;     // k -> h2Tpad
    float* Sb = (float*)(ws + off); off += SZ_S;      // scores -> V^T
    float* node = (float*)(ws + off); off += SZ_ACT_F; // node -> h (in place)
    bf16* VT = (bf16*)Sb;                              // V^T aliases score buffer
    (void)in_sizes; (void)n_in; (void)out_size;

    // Diagnostic guard: if ws is too small, fail cleanly (absmax ~8.5, no fault)
    if (ws_size < off) return;

    // ---- weight prep ----
    WtArgs wa;
    wa.src[0] = re_w; wa.src[1] = wq; wa.src[2] = wk; wa.src[3] = wv;
    wa.src[4] = wo;  wa.src[5] = fw1; wa.src[6] = fw2;
    for (int i = 0; i < 7; i++) wa.dst[i] = Wt[i];
    transpose7<<<dim3(40, 40, 7), dim3(32, 8), 0, stream>>>(wa);
    prep_conv<<<dim3(768), 256, 0, stream>>>(convw, bng, bnb, bnm, bnv, WconvT, bnscale, bnbias);

    // ---- rank ----
    rank_kernel<<<dim3(BC_), 256, 0, stream>>>(x, RP);

    const dim3 gBig(L_ / 128, BC_ / 128, 1);      // (10, 64)
    const dim3 gAttn(2, 2, 160);
    const dim3 blk(256);

    // ---- node = x + rank @ re_w + re_b (fp32) ----
    {
        GemmP p{}; p.zmod = 1; p.K = L_;
        p.A = RP; p.lda = L_; p.Bt = Wt[0]; p.ldb = L_;
        p.outF = node; p.ldc = L_; p.bias = re_b; p.res = x; p.ldres = L_;
        gemm_bt<E_F32_BIAS_RES><<<gBig, blk, 0, stream>>>(p);
    }
    // ---- LN1 -> y ----
    ln_kernel<<<dim3(BC_), blk, 0, stream>>>(node, ln1g, ln1b, Yb);
    // ---- Q (scaled), K ----
    {
        GemmP p{}; p.zmod = 1; p.K = L_;
        p.A = Yb; p.lda = L_; p.Bt = Wt[1]; p.ldb = L_;
        p.outB = Qb; p.ldc = L_; p.bias = bq; p.scale = 0.0625f;  // D^-0.5
        gemm_bt<E_BF16_BIAS_SCALE><<<gBig, blk, 0, stream>>>(p);
    }
    {
        GemmP p{}; p.zmod = 1; p.K = L_;
        p.A = Yb; p.lda = L_; p.Bt = Wt[2]; p.ldb = L_;
        p.outB = Kb; p.ldc = L_; p.bias = bk;
        gemm_bt<E_BF16_BIAS><<<gBig, blk, 0, stream>>>(p);
    }
    // ---- S = q k^T per (b,h) ----
    {
        GemmP p{}; p.zmod = H_; p.K = 256;
        p.A = Qb;  p.lda = L_; p.sA1 = (long)C_ * L_; p.sA2 = 256;
        p.Bt = Kb; p.ldb = L_; p.sB1 = (long)C_ * L_; p.sB2 = 256;
        p.outF = Sb; p.ldc = 256; p.sC1 = (long)H_ * 65536; p.sC2 = 65536;
        gemm_bt<E_F32><<<gAttn, blk, 0, stream>>>(p);
    }
    // ---- softmax -> P (into RP; rank is dead) ----
    softmax_kernel<<<dim3(160 * 256 / 4), blk, 0, stream>>>(Sb, RP);
    // ---- V (transposed, into VT = Sb region; scores are dead) ----
    {
        GemmP p{}; p.zmod = 1; p.K = L_;
        p.A = Yb; p.lda = L_; p.Bt = Wt[3]; p.ldb = L_;
        p.outB = VT; p.bias = bv;
        gemm_bt<E_VT><<<gBig, blk, 0, stream>>>(p);
    }
    // ---- O = P V  (into Qb; q is dead) ----
    {
        GemmP p{}; p.zmod = H_; p.K = 256;
        p.A = RP;  p.lda = 256; p.sA1 = (long)H_ * 65536; p.sA2 = 65536;
        p.Bt = VT; p.ldb = 256; p.sB1 = (long)H_ * 65536; p.sB2 = 65536;
        p.outB = Qb; p.ldc = L_; p.sC1 = (long)C_ * L_; p.sC2 = 256;
        gemm_bt<E_BF16><<<gAttn, blk, 0, stream>>>(p);
    }
    // ---- h = node + O @ wo + bo (fp32, in place over node) ----
    {
        GemmP p{}; p.zmod = 1; p.K = L_;
        p.A = Qb; p.lda = L_; p.Bt = Wt[4]; p.ldb = L_;
        p.outF = node; p.ldc = L_; p.bias = bo; p.res = node; p.ldres = L_;
        gemm_bt<E_F32_BIAS_RES><<<gBig, blk, 0, stream>>>(p);
    }
    // ---- LN2 -> y2 (RP; P is dead) ----
    ln_kernel<<<dim3(BC_), blk, 0, stream>>>(node, ln2g, ln2b, RP);
    // ---- f1 = gelu(y2 @ w1 + b1) (Yb; y is dead) ----
    {
        GemmP p{}; p.zmod = 1; p.K = L_;
        p.A = RP; p.lda = L_; p.Bt = Wt[5]; p.ldb = L_;
        p.outB = Yb; p.ldc = L_; p.bias = fb1;
        gemm_bt<E_GELU><<<gBig, blk, 0, stream>>>(p);
    }
    // ---- h2 = h + f1 @ w2 + b2 -> transposed+padded (Kb; k is dead) ----
    zero_pads<<<dim3(64), blk, 0, stream>>>(Kb);
    {
        GemmP p{}; p.zmod = 1; p.K = L_;
        p.A = Yb; p.lda = L_; p.Bt = Wt[6]; p.ldb = L_;
        p.outB = Kb; p.bias = fb2; p.res = node; p.ldres = L_;
        gemm_bt<E_FFN2T><<<gBig, blk, 0, stream>>>(p);
    }
    // ---- conv: single fused K=768 GEMM (taps read overlapping h2T rows) + BN + ReLU ----
    {
        GemmP p{}; p.zmod = 1; p.K = 768;
        p.A = WconvT; p.lda = 768;                       // [co][t*256+ci]
        p.Bt = Kb; p.ldb = 256; p.sB1 = 1282 * 256;      // row lc reads h2T rows lc..lc+2
        p.outF = out; p.ldc = L_; p.sC1 = (long)C_ * L_;
        p.rowscale = bnscale; p.rowbias = bnbias;
        gemm_bt<E_CONVBNR><<<dim3(L_ / 128, 2, B_), blk, 0, stream>>>(p);
    }
}

// Round 7
// 587.175 us; speedup vs baseline: 1.2104x; 1.1082x over previous
//
#include <hip/hip_runtime.h>
#include <hip/hip_bf16.h>
#include <stdint.h>

// Problem constants
#define L_   1280
#define B_   32
#define C_   256
#define H_   5
#define D_   256
#define BC_  8192            // B_*C_
#define EPSV 1e-5f

typedef __attribute__((ext_vector_type(8))) short bf16x8;   // 8 bf16 (4 VGPRs)
typedef __attribute__((ext_vector_type(4))) float f32x4;    // 4 fp32 acc
typedef __hip_bfloat16 bf16;

__device__ __forceinline__ bf16 f2bf(float v) { return __float2bfloat16(v); }

// async global->LDS, 16B per lane; LDS dest is wave-uniform base + lane*16
#define GLDS16(gptr, lptr)                                                        \
    __builtin_amdgcn_global_load_lds(                                             \
        (const __attribute__((address_space(1))) void*)(gptr),                    \
        (__attribute__((address_space(3))) void*)(lptr), 16, 0, 0)

// ---------------------------------------------------------------------------
// Weight prep: fp32 [K,N] -> bf16 [N,K] (transposed) for 7 LxL matrices
// ---------------------------------------------------------------------------
struct WtArgs { const float* src[7]; bf16* dst[7]; };

__global__ __launch_bounds__(256) void transpose7(WtArgs a) {
    const int mat = blockIdx.z;
    const float* src = a.src[mat];
    bf16* dst = a.dst[mat];
    __shared__ float tile[32][33];
    const int bx = blockIdx.x * 32;   // n base
    const int by = blockIdx.y * 32;   // k base
    const int tx = threadIdx.x, ty = threadIdx.y;
    #pragma unroll
    for (int r = ty; r < 32; r += 8)
        tile[r][tx] = src[(size_t)(by + r) * L_ + bx + tx];
    __syncthreads();
    #pragma unroll
    for (int r = ty; r < 32; r += 8)
        dst[(size_t)(bx + r) * L_ + by + tx] = f2bf(tile[tx][r]);
}

// conv weight pack: conv_w[co][ci][t] -> WT[co][t*256+ci]  (K=768 fused layout)
// plus BN scale/bias
__global__ __launch_bounds__(256) void prep_conv(const float* cw, const float* g, const float* b,
                                                 const float* m, const float* v,
                                                 bf16* WT, float* sc, float* bi) {
    const int i = blockIdx.x * 256 + threadIdx.x;
    if (i < 3 * 256 * 256) {
        const int co = i / 768;
        const int r = i - co * 768;
        const int t = r >> 8, ci = r & 255;
        WT[i] = f2bf(cw[(co * 256 + ci) * 3 + t]);
    }
    if (i < 256) {
        const float s = g[i] * rsqrtf(v[i] + EPSV);
        sc[i] = s;
        bi[i] = b[i] - m[i] * s;
    }
}

// ---------------------------------------------------------------------------
// Rank kernel (bucket-histogram; eq-before term dropped, < 2e-5 effect)
// ---------------------------------------------------------------------------
__global__ __launch_bounds__(256) void rank_kernel(const float* __restrict__ x, bf16* __restrict__ R) {
    __shared__ float vals[L_];
    __shared__ float sv[L_];
    __shared__ int hist[256];
    __shared__ int pfx[256];
    __shared__ int cur[256];
    const int row = blockIdx.x, tid = threadIdx.x;
    const float* src = x + (size_t)row * L_;
    for (int i = tid; i < L_; i += 256) vals[i] = src[i];
    hist[tid] = 0;
    __syncthreads();
    float myv[5]; int myb[5];
    #pragma unroll
    for (int ii = 0; ii < 5; ii++) {
        const float v = vals[tid + ii * 256];
        int bk = (int)((4.0f - v) * 32.0f);
        bk = bk < 0 ? 0 : (bk > 255 ? 255 : bk);
        myv[ii] = v; myb[ii] = bk;
        atomicAdd(&hist[bk], 1);
    }
    __syncthreads();
    pfx[tid] = hist[tid];
    __syncthreads();
    for (int off = 1; off < 256; off <<= 1) {
        int t = (tid >= off) ? pfx[tid - off] : 0;
        __syncthreads();
        pfx[tid] += t;
        __syncthreads();
    }
    cur[tid] = pfx[tid] - hist[tid];
    __syncthreads();
    #pragma unroll
    for (int ii = 0; ii < 5; ii++) {
        const int pos = atomicAdd(&cur[myb[ii]], 1);
        sv[pos] = myv[ii];
    }
    __syncthreads();
    #pragma unroll
    for (int ii = 0; ii < 5; ii++) {
        const int bk = myb[ii]; const float v = myv[ii];
        const int s = pfx[bk] - hist[bk], e = pfx[bk];
        int cg = s;
        for (int p = s; p < e; p++) cg += (sv[p] > v) ? 1 : 0;
        R[(size_t)row * L_ + tid + ii * 256] = f2bf((float)(L_ - cg) * (1.0f / L_));
    }
}

// ---------------------------------------------------------------------------
// LayerNorm over last dim (1280), fp32 in -> bf16 out
// ---------------------------------------------------------------------------
__global__ __launch_bounds__(256) void ln_kernel(const float* __restrict__ in,
                                                 const float* __restrict__ g,
                                                 const float* __restrict__ b,
                                                 bf16* __restrict__ out) {
    const int row = blockIdx.x, tid = threadIdx.x;
    const float* src = in + (size_t)row * L_;
    float4 va = ((const float4*)src)[tid];
    float s = va.x + va.y + va.z + va.w;
    float ss = va.x * va.x + va.y * va.y + va.z * va.z + va.w * va.w;
    float4 vb = {0, 0, 0, 0};
    if (tid < 64) {
        vb = ((const float4*)src)[256 + tid];
        s += vb.x + vb.y + vb.z + vb.w;
        ss += vb.x * vb.x + vb.y * vb.y + vb.z * vb.z + vb.w * vb.w;
    }
    #pragma unroll
    for (int off = 32; off > 0; off >>= 1) {
        s += __shfl_down(s, off, 64);
        ss += __shfl_down(ss, off, 64);
    }
    __shared__ float rs[4], rss[4];
    __shared__ float mean_s, rstd_s;
    if ((tid & 63) == 0) { rs[tid >> 6] = s; rss[tid >> 6] = ss; }
    __syncthreads();
    if (tid == 0) {
        const float S = rs[0] + rs[1] + rs[2] + rs[3];
        const float SS = rss[0] + rss[1] + rss[2] + rss[3];
        const float m = S * (1.0f / L_);
        const float var = SS * (1.0f / L_) - m * m;
        mean_s = m; rstd_s = rsqrtf(var + EPSV);
    }
    __syncthreads();
    const float m = mean_s, r = rstd_s;
    {
        const int c = tid * 4;
        bf16 t4[4];
        t4[0] = f2bf((va.x - m) * r * g[c + 0] + b[c + 0]);
        t4[1] = f2bf((va.y - m) * r * g[c + 1] + b[c + 1]);
        t4[2] = f2bf((va.z - m) * r * g[c + 2] + b[c + 2]);
        t4[3] = f2bf((va.w - m) * r * g[c + 3] + b[c + 3]);
        *(uint2*)(out + (size_t)row * L_ + c) = *(uint2*)t4;
    }
    if (tid < 64) {
        const int c = 1024 + tid * 4;
        bf16 t4[4];
        t4[0] = f2bf((vb.x - m) * r * g[c + 0] + b[c + 0]);
        t4[1] = f2bf((vb.y - m) * r * g[c + 1] + b[c + 1]);
        t4[2] = f2bf((vb.z - m) * r * g[c + 2] + b[c + 2]);
        t4[3] = f2bf((vb.w - m) * r * g[c + 3] + b[c + 3]);
        *(uint2*)(out + (size_t)row * L_ + c) = *(uint2*)t4;
    }
}

// ---------------------------------------------------------------------------
// Row softmax: 256 fp32 -> 256 bf16, one wave per row (4 rows / block)
// ---------------------------------------------------------------------------
__global__ __launch_bounds__(256) void softmax_kernel(const float* __restrict__ S, bf16* __restrict__ P) {
    const int row = blockIdx.x * 4 + (threadIdx.x >> 6);
    const int l = threadIdx.x & 63;
    const float4 v = *(const float4*)(S + (size_t)row * 256 + l * 4);
    float mx = fmaxf(fmaxf(v.x, v.y), fmaxf(v.z, v.w));
    #pragma unroll
    for (int off = 1; off < 64; off <<= 1) mx = fmaxf(mx, __shfl_xor(mx, off, 64));
    const float e0 = expf(v.x - mx), e1 = expf(v.y - mx), e2 = expf(v.z - mx), e3 = expf(v.w - mx);
    float sm = e0 + e1 + e2 + e3;
    #pragma unroll
    for (int off = 1; off < 64; off <<= 1) sm += __shfl_xor(sm, off, 64);
    const float inv = 1.0f / sm;
    bf16 t4[4] = { f2bf(e0 * inv), f2bf(e1 * inv), f2bf(e2 * inv), f2bf(e3 * inv) };
    *(uint2*)(P + (size_t)row * 256 + l * 4) = *(uint2*)t4;
}

// zero the two pad rows of h2Tpad [B][1282][256]
__global__ __launch_bounds__(256) void zero_pads(bf16* h2T) {
    const int i = blockIdx.x * 256 + threadIdx.x;   // 32*2*256 = 16384
    const int b = i >> 9;
    const int which = (i >> 8) & 1;
    const int ci = i & 255;
    const long row = which ? 1281 : 0;
    h2T[(long)b * (1282 * 256) + row * 256 + ci] = f2bf(0.0f);
}

// ---------------------------------------------------------------------------
// Generic batched GEMM: C[z][m][n] = sum_k A[z][m][k] * Bt[z][n][k]
// 128x128 tile, BK=32, 4 waves, mfma_f32_16x16x32_bf16.
// 2-phase double-buffered LDS (T3-minimal), global_load_lds width=16 staging,
// bijective XCD-chunked block swizzle (T1/m204).
// ---------------------------------------------------------------------------
struct GemmP {
    const bf16* A;  long lda, sA1, sA2;
    const bf16* Bt; long ldb, sB1, sB2;
    int zmod;
    int K;
    float* outF; bf16* outB; bf16* outB2; long ldc, sC1, sC2;
    const float* bias; const float* bias2;
    const float* res; long ldres, sR1, sR2;
    const float* rowscale; const float* rowbias;
    float scale;
};

constexpr int E_F32_BIAS_RES = 0;  // outF = acc + bias[col] + res (outF may == res)
constexpr int E_VT = 3;            // v-transpose store [b,h,d,c]
constexpr int E_F32 = 4;           // outF = acc       (with z offset)
constexpr int E_BF16 = 5;          // outB = bf16(acc) (with z offset)
constexpr int E_GELU = 6;          // outB = bf16(gelu(acc+bias))
constexpr int E_FFN2T = 7;         // h2 transposed+padded store
constexpr int E_CONVBNR = 8;       // relu(acc*rowscale+rowbias) -> outF
constexpr int E_QK = 9;            // cols<1280: Q=bf16((acc+bias)*scale); else K=bf16(acc+bias2)

template <int EPI>
__global__ __launch_bounds__(256) void gemm_bt(GemmP p) {
    // ---- bijective XCD-chunked swizzle (m204): contiguous grid chunk per XCD ----
    const int nwg  = gridDim.x * gridDim.y * gridDim.z;
    const int orig = (blockIdx.z * gridDim.y + blockIdx.y) * gridDim.x + blockIdx.x;
    const int qq = nwg >> 3, rr = nwg & 7;
    const int xcd = orig & 7, pos = orig >> 3;
    const int wgid = (xcd < rr ? xcd * (qq + 1) : rr * (qq + 1) + (xcd - rr) * qq) + pos;
    const int bx = wgid % gridDim.x;
    const int t1 = wgid / gridDim.x;
    const int by = t1 % gridDim.y;
    const int bz = t1 / gridDim.y;

    const int zq = bz / p.zmod, zr = bz % p.zmod;
    const bf16* A  = p.A  + (long)zq * p.sA1 + (long)zr * p.sA2;
    const bf16* Bt = p.Bt + (long)zq * p.sB1 + (long)zr * p.sB2;
    const int row0 = by * 128, col0 = bx * 128;

    __shared__ __align__(16) bf16 ldsA[2][128 * 32];
    __shared__ __align__(16) bf16 ldsB[2][128 * 32];

    const int tid = threadIdx.x;
    const int l = tid & 63, w = tid >> 6;
    const int wr = w >> 1, wc = w & 1;

    f32x4 acc[4][4];
    #pragma unroll
    for (int m = 0; m < 4; m++)
        #pragma unroll
        for (int n = 0; n < 4; n++)
            acc[m][n] = (f32x4){0.f, 0.f, 0.f, 0.f};

    const bf16* gA = A  + (long)(row0 + w * 16 + (l >> 2)) * p.lda + (l & 3) * 8;
    const bf16* gB = Bt + (long)(col0 + w * 16 + (l >> 2)) * p.ldb + (l & 3) * 8;
    const long aStep = 64 * p.lda, bStep = 64 * p.ldb;

    auto STAGE = [&](int buf) {
        GLDS16(gA,         &ldsA[buf][w * 512]);
        GLDS16(gA + aStep, &ldsA[buf][2048 + w * 512]);
        GLDS16(gB,         &ldsB[buf][w * 512]);
        GLDS16(gB + bStep, &ldsB[buf][2048 + w * 512]);
        gA += 32; gB += 32;
    };
    auto COMPUTE = [&](int buf) {
        bf16x8 aF[4], bF[4];
        #pragma unroll
        for (int m = 0; m < 4; m++)
            aF[m] = *(const bf16x8*)(&ldsA[buf][(wr * 64 + m * 16 + (l & 15)) * 32 + (l >> 4) * 8]);
        #pragma unroll
        for (int n = 0; n < 4; n++)
            bF[n] = *(const bf16x8*)(&ldsB[buf][(wc * 64 + n * 16 + (l & 15)) * 32 + (l >> 4) * 8]);
        #pragma unroll
        for (int m = 0; m < 4; m++)
            #pragma unroll
            for (int n = 0; n < 4; n++)
                acc[m][n] = __builtin_amdgcn_mfma_f32_16x16x32_bf16(aF[m], bF[n], acc[m][n], 0, 0, 0);
    };

    // ---- 2-phase pipeline: stage t+1 while computing t; one barrier/iter ----
    const int nt = p.K >> 5;
    STAGE(0);
    __syncthreads();                 // vmcnt(0) drain of prologue stage
    int cur = 0;
    for (int t = 0; t < nt - 1; ++t) {
        STAGE(cur ^ 1);              // next tile in flight
        COMPUTE(cur);                // hide load latency under ds_read+MFMA
        __syncthreads();             // drains this iter's stage; protects buf reuse
        cur ^= 1;
    }
    COMPUTE(cur);                    // last tile (already resident)

    const long cz = (long)zq * p.sC1 + (long)zr * p.sC2;
    const long rz = (long)zq * p.sR1 + (long)zr * p.sR2;
    #pragma unroll
    for (int m = 0; m < 4; m++) {
        #pragma unroll
        for (int n = 0; n < 4; n++) {
            const int gcol = col0 + wc * 64 + n * 16 + (l & 15);
            #pragma unroll
            for (int j = 0; j < 4; j++) {
                const int grow = row0 + wr * 64 + m * 16 + (l >> 4) * 4 + j;
                const float v = acc[m][n][j];
                if constexpr (EPI == E_F32_BIAS_RES) {
                    p.outF[cz + (long)grow * p.ldc + gcol] =
                        v + p.bias[gcol] + p.res[rz + (long)grow * p.ldres + gcol];
                } else if constexpr (EPI == E_VT) {
                    const int b_ = grow >> 8, c_ = grow & 255;
                    const int h_ = gcol >> 8, d_ = gcol & 255;
                    p.outB[(((long)(b_ * H_ + h_) * 256 + d_) << 8) + c_] = f2bf(v + p.bias[gcol]);
                } else if constexpr (EPI == E_F32) {
                    p.outF[cz + (long)grow * p.ldc + gcol] = v;
                } else if constexpr (EPI == E_BF16) {
                    p.outB[cz + (long)grow * p.ldc + gcol] = f2bf(v);
                } else if constexpr (EPI == E_GELU) {
                    const float t = v + p.bias[gcol];
                    p.outB[cz + (long)grow * p.ldc + gcol] =
                        f2bf(0.5f * t * (1.0f + erff(t * 0.70710678f)));
                } else if constexpr (EPI == E_FFN2T) {
                    const float t = v + p.bias[gcol] + p.res[rz + (long)grow * p.ldres + gcol];
                    const int b_ = grow >> 8, ci = grow & 255;
                    p.outB[(long)b_ * (1282 * 256) + (long)(gcol + 1) * 256 + ci] = f2bf(t);
                } else if constexpr (EPI == E_CONVBNR) {
                    const float t = v * p.rowscale[grow] + p.rowbias[grow];
                    p.outF[cz + (long)grow * p.ldc + gcol] = fmaxf(t, 0.0f);
                } else if constexpr (EPI == E_QK) {
                    if (gcol < 1280) {
                        p.outB[(long)grow * L_ + gcol] = f2bf((v + p.bias[gcol]) * p.scale);
                    } else {
                        const int c2 = gcol - 1280;
                        p.outB2[(long)grow * L_ + c2] = f2bf(v + p.bias2[c2]);
                    }
                }
            }
        }
    }
}

// ---------------------------------------------------------------------------
extern "C" void kernel_launch(void* const* d_in, const int* in_sizes, int n_in,
                              void* d_out, int out_size, void* d_ws, size_t ws_size,
                              hipStream_t stream) {
    const float* x    = (const float*)d_in[0];
    const float* re_w = (const float*)d_in[1];
    const float* re_b = (const float*)d_in[2];
    const float* ln1g = (const float*)d_in[3];
    const float* ln1b = (const float*)d_in[4];
    const float* ln2g = (const float*)d_in[5];
    const float* ln2b = (const float*)d_in[6];
    const float* wq   = (const float*)d_in[7];
    const float* bq   = (const float*)d_in[8];
    const float* wk   = (const float*)d_in[9];
    const float* bk   = (const float*)d_in[10];
    const float* wv   = (const float*)d_in[11];
    const float* bv   = (const float*)d_in[12];
    const float* wo   = (const float*)d_in[13];
    const float* bo   = (const float*)d_in[14];
    const float* fw1  = (const float*)d_in[15];
    const float* fb1  = (const float*)d_in[16];
    const float* fw2  = (const float*)d_in[17];
    const float* fb2  = (const float*)d_in[18];
    const float* convw = (const float*)d_in[19];
    const float* bng  = (const float*)d_in[20];
    const float* bnb  = (const float*)d_in[21];
    const float* bnm  = (const float*)d_in[22];
    const float* bnv  = (const float*)d_in[23];
    float* out = (float*)d_out;

    // ---- workspace layout (total 191,137,792 bytes) ----
    char* ws = (char*)d_ws;
    const size_t SZ_WT     = (size_t)L_ * L_ * 2;          // 3,276,800
    const size_t SZ_ACT_BF = (size_t)BC_ * L_ * 2;         // 20,971,520
    const size_t SZ_ACT_F  = (size_t)BC_ * L_ * 4;         // 41,943,040
    const size_t SZ_H2T    = (size_t)B_ * 1282 * 256 * 2;  // 21,004,288
    const size_t SZ_S      = (size_t)160 * 256 * 256 * 4;  // 41,943,040

    size_t off = 0;
    bf16* Wt[7];
    for (int i = 0; i < 7; i++) { Wt[i] = (bf16*)(ws + off); off += SZ_WT; }  // contiguous!
    bf16* WconvT   = (bf16*)(ws + off); off += 393216;
    float* bnscale = (float*)(ws + off); off += 1024;
    float* bnbias  = (float*)(ws + off); off += 1024;
    bf16* RP  = (bf16*)(ws + off); off += SZ_ACT_BF;  // rank -> P -> y2
    bf16* Yb  = (bf16*)(ws + off); off += SZ_ACT_BF;  // y -> f1
    bf16* Qb  = (bf16*)(ws + off); off += SZ_ACT_BF;  // q -> attn O
    bf16* Kb  = (bf16*)(ws + off); off += SZ_H2T;     // k -> h2Tpad
    float* Sb = (float*)(ws + off); off += SZ_S;      // scores -> V^T
    float* node = (float*)(ws + off); off += SZ_ACT_F; // node -> h (in place)
    bf16* VT = (bf16*)Sb;                              // V^T aliases score buffer
    (void)in_sizes; (void)n_in; (void)out_size;

    // Diagnostic guard: if ws is too small, fail cleanly (absmax ~8.5, no fault)
    if (ws_size < off) return;

    // ---- weight prep ----
    WtArgs wa;
    wa.src[0] = re_w; wa.src[1] = wq; wa.src[2] = wk; wa.src[3] = wv;
    wa.src[4] = wo;  wa.src[5] = fw1; wa.src[6] = fw2;
    for (int i = 0; i < 7; i++) wa.dst[i] = Wt[i];
    transpose7<<<dim3(40, 40, 7), dim3(32, 8), 0, stream>>>(wa);
    prep_conv<<<dim3(768), 256, 0, stream>>>(convw, bng, bnb, bnm, bnv, WconvT, bnscale, bnbias);

    // ---- rank ----
    rank_kernel<<<dim3(BC_), 256, 0, stream>>>(x, RP);

    const dim3 gBig(L_ / 128, BC_ / 128, 1);      // (10, 64)
    const dim3 gQK(2560 / 128, BC_ / 128, 1);     // (20, 64)
    const dim3 gAttn(2, 2, 160);
    const dim3 blk(256);

    // ---- node = x + rank @ re_w + re_b (fp32) ----
    {
        GemmP p{}; p.zmod = 1; p.K = L_;
        p.A = RP; p.lda = L_; p.Bt = Wt[0]; p.ldb = L_;
        p.outF = node; p.ldc = L_; p.bias = re_b; p.res = x; p.ldres = L_;
        gemm_bt<E_F32_BIAS_RES><<<gBig, blk, 0, stream>>>(p);
    }
    // ---- LN1 -> y ----
    ln_kernel<<<dim3(BC_), blk, 0, stream>>>(node, ln1g, ln1b, Yb);
    // ---- Q (scaled) + K fused: Bt rows 0..2559 = Wt[1] || Wt[2] (contiguous) ----
    {
        GemmP p{}; p.zmod = 1; p.K = L_;
        p.A = Yb; p.lda = L_; p.Bt = Wt[1]; p.ldb = L_;
        p.outB = Qb; p.outB2 = Kb; p.bias = bq; p.bias2 = bk; p.scale = 0.0625f;
        gemm_bt<E_QK><<<gQK, blk, 0, stream>>>(p);
    }
    // ---- S = q k^T per (b,h) ----
    {
        GemmP p{}; p.zmod = H_; p.K = 256;
        p.A = Qb;  p.lda = L_; p.sA1 = (long)C_ * L_; p.sA2 = 256;
        p.Bt = Kb; p.ldb = L_; p.sB1 = (long)C_ * L_; p.sB2 = 256;
        p.outF = Sb; p.ldc = 256; p.sC1 = (long)H_ * 65536; p.sC2 = 65536;
        gemm_bt<E_F32><<<gAttn, blk, 0, stream>>>(p);
    }
    // ---- softmax -> P (into RP; rank is dead) ----
    softmax_kernel<<<dim3(160 * 256 / 4), blk, 0, stream>>>(Sb, RP);
    // ---- V (transposed, into VT = Sb region; scores are dead) ----
    {
        GemmP p{}; p.zmod = 1; p.K = L_;
        p.A = Yb; p.lda = L_; p.Bt = Wt[3]; p.ldb = L_;
        p.outB = VT; p.bias = bv;
        gemm_bt<E_VT><<<gBig, blk, 0, stream>>>(p);
    }
    // ---- O = P V  (into Qb; q is dead) ----
    {
        GemmP p{}; p.zmod = H_; p.K = 256;
        p.A = RP;  p.lda = 256; p.sA1 = (long)H_ * 65536; p.sA2 = 65536;
        p.Bt = VT; p.ldb = 256; p.sB1 = (long)H_ * 65536; p.sB2 = 65536;
        p.outB = Qb; p.ldc = L_; p.sC1 = (long)C_ * L_; p.sC2 = 256;
        gemm_bt<E_BF16><<<gAttn, blk, 0, stream>>>(p);
    }
    // ---- h = node + O @ wo + bo (fp32, in place over node) ----
    {
        GemmP p{}; p.zmod = 1; p.K = L_;
        p.A = Qb; p.lda = L_; p.Bt = Wt[4]; p.ldb = L_;
        p.outF = node; p.ldc = L_; p.bias = bo; p.res = node; p.ldres = L_;
        gemm_bt<E_F32_BIAS_RES><<<gBig, blk, 0, stream>>>(p);
    }
    // ---- LN2 -> y2 (RP; P is dead) ----
    ln_kernel<<<dim3(BC_), blk, 0, stream>>>(node, ln2g, ln2b, RP);
    // ---- f1 = gelu(y2 @ w1 + b1) (Yb; y is dead) ----
    {
        GemmP p{}; p.zmod = 1; p.K = L_;
        p.A = RP; p.lda = L_; p.Bt = Wt[5]; p.ldb = L_;
        p.outB = Yb; p.ldc = L_; p.bias = fb1;
        gemm_bt<E_GELU><<<gBig, blk, 0, stream>>>(p);
    }
    // ---- h2 = h + f1 @ w2 + b2 -> transposed+padded (Kb; k is dead) ----
    zero_pads<<<dim3(64), blk, 0, stream>>>(Kb);
    {
        GemmP p{}; p.zmod = 1; p.K = L_;
        p.A = Yb; p.lda = L_; p.Bt = Wt[6]; p.ldb = L_;
        p.outB = Kb; p.bias = fb2; p.res = node; p.ldres = L_;
        gemm_bt<E_FFN2T><<<gBig, blk, 0, stream>>>(p);
    }
    // ---- conv: single fused K=768 GEMM + BN + ReLU ----
    {
        GemmP p{}; p.zmod = 1; p.K = 768;
        p.A = WconvT; p.lda = 768;                       // [co][t*256+ci]
        p.Bt = Kb; p.ldb = 256; p.sB1 = 1282 * 256;      // row lc reads h2T rows lc..lc+2
        p.outF = out; p.ldc = L_; p.sC1 = (long)C_ * L_;
        p.rowscale = bnscale; p.rowbias = bnbias;
        gemm_bt<E_CONVBNR><<<dim3(L_ / 128, 2, B_), blk, 0, stream>>>(p);
    }
}

// Round 9
// 554.183 us; speedup vs baseline: 1.2824x; 1.0595x over previous
//
#include <hip/hip_runtime.h>
#include <hip/hip_bf16.h>
#include <stdint.h>

// Problem constants
#define L_   1280
#define B_   32
#define C_   256
#define H_   5
#define D_   256
#define BC_  8192            // B_*C_
#define EPSV 1e-5f

typedef __attribute__((ext_vector_type(8))) short bf16x8;   // 8 bf16 (4 VGPRs)
typedef __attribute__((ext_vector_type(4))) float f32x4;    // 4 fp32 acc
typedef __hip_bfloat16 bf16;

__device__ __forceinline__ bf16 f2bf(float v) { return __float2bfloat16(v); }

// async global->LDS, 16B per lane; LDS dest is wave-uniform base + lane*16
#define GLDS16(gptr, lptr)                                                        \
    __builtin_amdgcn_global_load_lds(                                             \
        (const __attribute__((address_space(1))) void*)(gptr),                    \
        (__attribute__((address_space(3))) void*)(lptr), 16, 0, 0)

// ---------------------------------------------------------------------------
// Weight prep: fp32 [K,N] -> bf16 [N,K] (transposed) for 7 LxL matrices
// ---------------------------------------------------------------------------
struct WtArgs { const float* src[7]; bf16* dst[7]; };

__global__ __launch_bounds__(256) void transpose7(WtArgs a) {
    const int mat = blockIdx.z;
    const float* src = a.src[mat];
    bf16* dst = a.dst[mat];
    __shared__ float tile[32][33];
    const int bx = blockIdx.x * 32;   // n base
    const int by = blockIdx.y * 32;   // k base
    const int tx = threadIdx.x, ty = threadIdx.y;
    #pragma unroll
    for (int r = ty; r < 32; r += 8)
        tile[r][tx] = src[(size_t)(by + r) * L_ + bx + tx];
    __syncthreads();
    #pragma unroll
    for (int r = ty; r < 32; r += 8)
        dst[(size_t)(bx + r) * L_ + by + tx] = f2bf(tile[tx][r]);
}

// conv weight pack: conv_w[co][ci][t] -> WT[co][t*256+ci]  (K=768 fused layout)
// plus BN scale/bias
__global__ __launch_bounds__(256) void prep_conv(const float* cw, const float* g, const float* b,
                                                 const float* m, const float* v,
                                                 bf16* WT, float* sc, float* bi) {
    const int i = blockIdx.x * 256 + threadIdx.x;
    if (i < 3 * 256 * 256) {
        const int co = i / 768;
        const int r = i - co * 768;
        const int t = r >> 8, ci = r & 255;
        WT[i] = f2bf(cw[(co * 256 + ci) * 3 + t]);
    }
    if (i < 256) {
        const float s = g[i] * rsqrtf(v[i] + EPSV);
        sc[i] = s;
        bi[i] = b[i] - m[i] * s;
    }
}

// ---------------------------------------------------------------------------
// Rank kernel (bucket-histogram; eq-before term dropped, < 2e-5 effect)
// ---------------------------------------------------------------------------
__global__ __launch_bounds__(256) void rank_kernel(const float* __restrict__ x, bf16* __restrict__ R) {
    __shared__ float vals[L_];
    __shared__ float sv[L_];
    __shared__ int hist[256];
    __shared__ int pfx[256];
    __shared__ int cur[256];
    const int row = blockIdx.x, tid = threadIdx.x;
    const float* src = x + (size_t)row * L_;
    for (int i = tid; i < L_; i += 256) vals[i] = src[i];
    hist[tid] = 0;
    __syncthreads();
    float myv[5]; int myb[5];
    #pragma unroll
    for (int ii = 0; ii < 5; ii++) {
        const float v = vals[tid + ii * 256];
        int bk = (int)((4.0f - v) * 32.0f);
        bk = bk < 0 ? 0 : (bk > 255 ? 255 : bk);
        myv[ii] = v; myb[ii] = bk;
        atomicAdd(&hist[bk], 1);
    }
    __syncthreads();
    pfx[tid] = hist[tid];
    __syncthreads();
    for (int off = 1; off < 256; off <<= 1) {
        int t = (tid >= off) ? pfx[tid - off] : 0;
        __syncthreads();
        pfx[tid] += t;
        __syncthreads();
    }
    cur[tid] = pfx[tid] - hist[tid];
    __syncthreads();
    #pragma unroll
    for (int ii = 0; ii < 5; ii++) {
        const int pos = atomicAdd(&cur[myb[ii]], 1);
        sv[pos] = myv[ii];
    }
    __syncthreads();
    #pragma unroll
    for (int ii = 0; ii < 5; ii++) {
        const int bk = myb[ii]; const float v = myv[ii];
        const int s = pfx[bk] - hist[bk], e = pfx[bk];
        int cg = s;
        for (int p = s; p < e; p++) cg += (sv[p] > v) ? 1 : 0;
        R[(size_t)row * L_ + tid + ii * 256] = f2bf((float)(L_ - cg) * (1.0f / L_));
    }
}

// ---------------------------------------------------------------------------
// LayerNorm over last dim (1280), fp32 in -> bf16 out
// ---------------------------------------------------------------------------
__global__ __launch_bounds__(256) void ln_kernel(const float* __restrict__ in,
                                                 const float* __restrict__ g,
                                                 const float* __restrict__ b,
                                                 bf16* __restrict__ out) {
    const int row = blockIdx.x, tid = threadIdx.x;
    const float* src = in + (size_t)row * L_;
    float4 va = ((const float4*)src)[tid];
    float s = va.x + va.y + va.z + va.w;
    float ss = va.x * va.x + va.y * va.y + va.z * va.z + va.w * va.w;
    float4 vb = {0, 0, 0, 0};
    if (tid < 64) {
        vb = ((const float4*)src)[256 + tid];
        s += vb.x + vb.y + vb.z + vb.w;
        ss += vb.x * vb.x + vb.y * vb.y + vb.z * vb.z + vb.w * vb.w;
    }
    #pragma unroll
    for (int off = 32; off > 0; off >>= 1) {
        s += __shfl_down(s, off, 64);
        ss += __shfl_down(ss, off, 64);
    }
    __shared__ float rs[4], rss[4];
    __shared__ float mean_s, rstd_s;
    if ((tid & 63) == 0) { rs[tid >> 6] = s; rss[tid >> 6] = ss; }
    __syncthreads();
    if (tid == 0) {
        const float S = rs[0] + rs[1] + rs[2] + rs[3];
        const float SS = rss[0] + rss[1] + rss[2] + rss[3];
        const float m = S * (1.0f / L_);
        const float var = SS * (1.0f / L_) - m * m;
        mean_s = m; rstd_s = rsqrtf(var + EPSV);
    }
    __syncthreads();
    const float m = mean_s, r = rstd_s;
    {
        const int c = tid * 4;
        bf16 t4[4];
        t4[0] = f2bf((va.x - m) * r * g[c + 0] + b[c + 0]);
        t4[1] = f2bf((va.y - m) * r * g[c + 1] + b[c + 1]);
        t4[2] = f2bf((va.z - m) * r * g[c + 2] + b[c + 2]);
        t4[3] = f2bf((va.w - m) * r * g[c + 3] + b[c + 3]);
        *(uint2*)(out + (size_t)row * L_ + c) = *(uint2*)t4;
    }
    if (tid < 64) {
        const int c = 1024 + tid * 4;
        bf16 t4[4];
        t4[0] = f2bf((vb.x - m) * r * g[c + 0] + b[c + 0]);
        t4[1] = f2bf((vb.y - m) * r * g[c + 1] + b[c + 1]);
        t4[2] = f2bf((vb.z - m) * r * g[c + 2] + b[c + 2]);
        t4[3] = f2bf((vb.w - m) * r * g[c + 3] + b[c + 3]);
        *(uint2*)(out + (size_t)row * L_ + c) = *(uint2*)t4;
    }
}

// ---------------------------------------------------------------------------
// Row softmax: 256 bf16 logits -> 256 bf16 probs, one wave per row
// ---------------------------------------------------------------------------
__global__ __launch_bounds__(256) void softmax_kernel(const bf16* __restrict__ S, bf16* __restrict__ P) {
    const int row = blockIdx.x * 4 + (threadIdx.x >> 6);
    const int l = threadIdx.x & 63;
    const bf16* src = S + (size_t)row * 256 + l * 4;
    uint2 raw = *(const uint2*)src;
    bf16 s4[4]; *(uint2*)s4 = raw;
    float v0 = __bfloat162float(s4[0]), v1 = __bfloat162float(s4[1]);
    float v2 = __bfloat162float(s4[2]), v3 = __bfloat162float(s4[3]);
    float mx = fmaxf(fmaxf(v0, v1), fmaxf(v2, v3));
    #pragma unroll
    for (int off = 1; off < 64; off <<= 1) mx = fmaxf(mx, __shfl_xor(mx, off, 64));
    const float e0 = expf(v0 - mx), e1 = expf(v1 - mx), e2 = expf(v2 - mx), e3 = expf(v3 - mx);
    float sm = e0 + e1 + e2 + e3;
    #pragma unroll
    for (int off = 1; off < 64; off <<= 1) sm += __shfl_xor(sm, off, 64);
    const float inv = 1.0f / sm;
    bf16 t4[4] = { f2bf(e0 * inv), f2bf(e1 * inv), f2bf(e2 * inv), f2bf(e3 * inv) };
    *(uint2*)(P + (size_t)row * 256 + l * 4) = *(uint2*)t4;
}

// zero the two pad rows of h2Tpad [B][1282][256]
__global__ __launch_bounds__(256) void zero_pads(bf16* h2T) {
    const int i = blockIdx.x * 256 + threadIdx.x;   // 32*2*256 = 16384
    const int b = i >> 9;
    const int which = (i >> 8) & 1;
    const int ci = i & 255;
    const long row = which ? 1281 : 0;
    h2T[(long)b * (1282 * 256) + row * 256 + ci] = f2bf(0.0f);
}

// ---------------------------------------------------------------------------
// Generic batched GEMM: C[z][m][n] = sum_k A[z][m][k] * Bt[z][n][k]
// 128x128 tile, BK=32, 4 waves, mfma_f32_16x16x32_bf16.
// Counted-vmcnt 2-phase pipeline (T4): loads stay in flight across barriers.
// global_load_lds width=16 staging; bijective XCD-chunked swizzle (T1/m204).
// ---------------------------------------------------------------------------
struct GemmP {
    const bf16* A;  long lda, sA1, sA2;
    const bf16* Bt; long ldb, sB1, sB2;
    int zmod;
    int K;
    float* outF; bf16* outB; bf16* outB2; bf16* outB3; long ldc, sC1, sC2;
    const float* bias; const float* bias2; const float* bias3;
    const float* res; long ldres, sR1, sR2;
    const float* rowscale; const float* rowbias;
    float scale;
};

constexpr int E_F32_BIAS_RES = 0;  // outF = acc + bias[col] + res (outF may == res)
constexpr int E_F32 = 4;           // outF = acc       (with z offset)
constexpr int E_BF16 = 5;          // outB = bf16(acc) (with z offset)
constexpr int E_GELU = 6;          // outB = bf16(gelu(acc+bias))
constexpr int E_FFN2T = 7;         // h2 transposed+padded store
constexpr int E_CONVBNR = 8;       // relu(acc*rowscale+rowbias) -> outF
constexpr int E_QKV = 9;           // col<1280: Q*scale; <2560: K; else V-transposed

template <int EPI>
__global__ __launch_bounds__(256) void gemm_bt(GemmP p) {
    // ---- bijective XCD-chunked swizzle (m204): contiguous grid chunk per XCD ----
    const int nwg  = gridDim.x * gridDim.y * gridDim.z;
    const int orig = (blockIdx.z * gridDim.y + blockIdx.y) * gridDim.x + blockIdx.x;
    const int qq = nwg >> 3, rr = nwg & 7;
    const int xcd = orig & 7, pos = orig >> 3;
    const int wgid = (xcd < rr ? xcd * (qq + 1) : rr * (qq + 1) + (xcd - rr) * qq) + pos;
    const int bx = wgid % gridDim.x;
    const int t1 = wgid / gridDim.x;
    const int by = t1 % gridDim.y;
    const int bz = t1 / gridDim.y;

    const int zq = bz / p.zmod, zr = bz % p.zmod;
    const bf16* A  = p.A  + (long)zq * p.sA1 + (long)zr * p.sA2;
    const bf16* Bt = p.Bt + (long)zq * p.sB1 + (long)zr * p.sB2;
    const int row0 = by * 128, col0 = bx * 128;

    __shared__ __align__(16) bf16 ldsA[2][128 * 32];
    __shared__ __align__(16) bf16 ldsB[2][128 * 32];

    const int tid = threadIdx.x;
    const int l = tid & 63, w = tid >> 6;
    const int wr = w >> 1, wc = w & 1;

    f32x4 acc[4][4];
    #pragma unroll
    for (int m = 0; m < 4; m++)
        #pragma unroll
        for (int n = 0; n < 4; n++)
            acc[m][n] = (f32x4){0.f, 0.f, 0.f, 0.f};

    const bf16* gA = A  + (long)(row0 + w * 16 + (l >> 2)) * p.lda + (l & 3) * 8;
    const bf16* gB = Bt + (long)(col0 + w * 16 + (l >> 2)) * p.ldb + (l & 3) * 8;
    const long aStep = 64 * p.lda, bStep = 64 * p.ldb;

    auto STAGE = [&](int buf) {
        GLDS16(gA,         &ldsA[buf][w * 512]);
        GLDS16(gA + aStep, &ldsA[buf][2048 + w * 512]);
        GLDS16(gB,         &ldsB[buf][w * 512]);
        GLDS16(gB + bStep, &ldsB[buf][2048 + w * 512]);
        gA += 32; gB += 32;
    };
    auto COMPUTE = [&](int buf) {
        bf16x8 aF[4], bF[4];
        #pragma unroll
        for (int m = 0; m < 4; m++)
            aF[m] = *(const bf16x8*)(&ldsA[buf][(wr * 64 + m * 16 + (l & 15)) * 32 + (l >> 4) * 8]);
        #pragma unroll
        for (int n = 0; n < 4; n++)
            bF[n] = *(const bf16x8*)(&ldsB[buf][(wc * 64 + n * 16 + (l & 15)) * 32 + (l >> 4) * 8]);
        #pragma unroll
        for (int m = 0; m < 4; m++)
            #pragma unroll
            for (int n = 0; n < 4; n++)
                acc[m][n] = __builtin_amdgcn_mfma_f32_16x16x32_bf16(aF[m], bF[n], acc[m][n], 0, 0, 0);
    };

    // ---- counted-vmcnt 2-phase pipeline: never drain the just-issued stage ----
    const int nt = p.K >> 5;
    STAGE(0);                                        // tile 0 in flight (4 loads)
    int cur = 0;
    for (int t = 0; t < nt - 1; ++t) {
        STAGE(cur ^ 1);                              // tile t+1 in flight (8 outstanding)
        asm volatile("s_waitcnt vmcnt(4)" ::: "memory");   // wait ONLY tile-t loads
        __builtin_amdgcn_sched_barrier(0);
        __builtin_amdgcn_s_barrier();                // all waves: buf[cur] ready
        COMPUTE(cur);
        __builtin_amdgcn_sched_barrier(0);
        __builtin_amdgcn_s_barrier();                // all waves done reading buf[cur]
        cur ^= 1;
    }
    asm volatile("s_waitcnt vmcnt(0)" ::: "memory");
    __builtin_amdgcn_sched_barrier(0);
    __builtin_amdgcn_s_barrier();
    COMPUTE(cur);                                    // last tile

    const long cz = (long)zq * p.sC1 + (long)zr * p.sC2;
    const long rz = (long)zq * p.sR1 + (long)zr * p.sR2;
    #pragma unroll
    for (int m = 0; m < 4; m++) {
        #pragma unroll
        for (int n = 0; n < 4; n++) {
            const int gcol = col0 + wc * 64 + n * 16 + (l & 15);
            #pragma unroll
            for (int j = 0; j < 4; j++) {
                const int grow = row0 + wr * 64 + m * 16 + (l >> 4) * 4 + j;
                const float v = acc[m][n][j];
                if constexpr (EPI == E_F32_BIAS_RES) {
                    p.outF[cz + (long)grow * p.ldc + gcol] =
                        v + p.bias[gcol] + p.res[rz + (long)grow * p.ldres + gcol];
                } else if constexpr (EPI == E_F32) {
                    p.outF[cz + (long)grow * p.ldc + gcol] = v;
                } else if constexpr (EPI == E_BF16) {
                    p.outB[cz + (long)grow * p.ldc + gcol] = f2bf(v);
                } else if constexpr (EPI == E_GELU) {
                    const float t = v + p.bias[gcol];
                    p.outB[cz + (long)grow * p.ldc + gcol] =
                        f2bf(0.5f * t * (1.0f + erff(t * 0.70710678f)));
                } else if constexpr (EPI == E_FFN2T) {
                    const float t = v + p.bias[gcol] + p.res[rz + (long)grow * p.ldres + gcol];
                    const int b_ = grow >> 8, ci = grow & 255;
                    p.outB[(long)b_ * (1282 * 256) + (long)(gcol + 1) * 256 + ci] = f2bf(t);
                } else if constexpr (EPI == E_CONVBNR) {
                    const float t = v * p.rowscale[grow] + p.rowbias[grow];
                    p.outF[cz + (long)grow * p.ldc + gcol] = fmaxf(t, 0.0f);
                } else if constexpr (EPI == E_QKV) {
                    if (gcol < 1280) {                       // Q (scaled)
                        p.outB[(long)grow * L_ + gcol] = f2bf((v + p.bias[gcol]) * p.scale);
                    } else if (gcol < 2560) {                // K
                        const int c2 = gcol - 1280;
                        p.outB2[(long)grow * L_ + c2] = f2bf(v + p.bias2[c2]);
                    } else {                                 // V -> [b,h,d,c]
                        const int c3 = gcol - 2560;
                        const int b_ = grow >> 8, c_ = grow & 255;
                        const int h_ = c3 >> 8, d_ = c3 & 255;
                        p.outB3[(((long)(b_ * H_ + h_) * 256 + d_) << 8) + c_] =
                            f2bf(v + p.bias3[c3]);
                    }
                }
            }
        }
    }
}

// ---------------------------------------------------------------------------
extern "C" void kernel_launch(void* const* d_in, const int* in_sizes, int n_in,
                              void* d_out, int out_size, void* d_ws, size_t ws_size,
                              hipStream_t stream) {
    const float* x    = (const float*)d_in[0];
    const float* re_w = (const float*)d_in[1];
    const float* re_b = (const float*)d_in[2];
    const float* ln1g = (const float*)d_in[3];
    const float* ln1b = (const float*)d_in[4];
    const float* ln2g = (const float*)d_in[5];
    const float* ln2b = (const float*)d_in[6];
    const float* wq   = (const float*)d_in[7];
    const float* bq   = (const float*)d_in[8];
    const float* wk   = (const float*)d_in[9];
    const float* bk   = (const float*)d_in[10];
    const float* wv   = (const float*)d_in[11];
    const float* bv   = (const float*)d_in[12];
    const float* wo   = (const float*)d_in[13];
    const float* bo   = (const float*)d_in[14];
    const float* fw1  = (const float*)d_in[15];
    const float* fb1  = (const float*)d_in[16];
    const float* fw2  = (const float*)d_in[17];
    const float* fb2  = (const float*)d_in[18];
    const float* convw = (const float*)d_in[19];
    const float* bng  = (const float*)d_in[20];
    const float* bnb  = (const float*)d_in[21];
    const float* bnm  = (const float*)d_in[22];
    const float* bnv  = (const float*)d_in[23];
    float* out = (float*)d_out;

    // ---- workspace layout (total 191,137,792 bytes) ----
    char* ws = (char*)d_ws;
    const size_t SZ_WT     = (size_t)L_ * L_ * 2;          // 3,276,800
    const size_t SZ_ACT_BF = (size_t)BC_ * L_ * 2;         // 20,971,520
    const size_t SZ_ACT_F  = (size_t)BC_ * L_ * 4;         // 41,943,040
    const size_t SZ_H2T    = (size_t)B_ * 1282 * 256 * 2;  // 21,004,288
    const size_t SZ_S      = (size_t)160 * 256 * 256 * 4;  // 41,943,040

    size_t off = 0;
    bf16* Wt[7];
    for (int i = 0; i < 7; i++) { Wt[i] = (bf16*)(ws + off); off += SZ_WT; }  // contiguous!
    bf16* WconvT   = (bf16*)(ws + off); off += 393216;
    float* bnscale = (float*)(ws + off); off += 1024;
    float* bnbias  = (float*)(ws + off); off += 1024;
    bf16* RP  = (bf16*)(ws + off); off += SZ_ACT_BF;  // rank -> P -> y2
    bf16* Yb  = (bf16*)(ws + off); off += SZ_ACT_BF;  // y -> f1
    bf16* Qb  = (bf16*)(ws + off); off += SZ_ACT_BF;  // q -> attn O
    bf16* Kb  = (bf16*)(ws + off); off += SZ_H2T;     // k -> h2Tpad
    float* Sb = (float*)(ws + off); off += SZ_S;      // [Sbf16 21MB][VT 21MB]
    float* node = (float*)(ws + off); off += SZ_ACT_F; // node -> h (in place)
    bf16* Sbf = (bf16*)Sb;                             // bf16 scores, first half
    bf16* VT  = Sbf + (size_t)160 * 65536;             // V^T, second half
    (void)in_sizes; (void)n_in; (void)out_size;

    // Diagnostic guard: if ws is too small, fail cleanly (absmax ~8.5, no fault)
    if (ws_size < off) return;

    // ---- weight prep ----
    WtArgs wa;
    wa.src[0] = re_w; wa.src[1] = wq; wa.src[2] = wk; wa.src[3] = wv;
    wa.src[4] = wo;  wa.src[5] = fw1; wa.src[6] = fw2;
    for (int i = 0; i < 7; i++) wa.dst[i] = Wt[i];
    transpose7<<<dim3(40, 40, 7), dim3(32, 8), 0, stream>>>(wa);
    prep_conv<<<dim3(768), 256, 0, stream>>>(convw, bng, bnb, bnm, bnv, WconvT, bnscale, bnbias);

    // ---- rank ----
    rank_kernel<<<dim3(BC_), 256, 0, stream>>>(x, RP);

    const dim3 gBig(L_ / 128, BC_ / 128, 1);      // (10, 64)
    const dim3 gQKV(3840 / 128, BC_ / 128, 1);    // (30, 64)
    const dim3 gAttn(2, 2, 160);
    const dim3 blk(256);

    // ---- node = x + rank @ re_w + re_b (fp32) ----
    {
        GemmP p{}; p.zmod = 1; p.K = L_;
        p.A = RP; p.lda = L_; p.Bt = Wt[0]; p.ldb = L_;
        p.outF = node; p.ldc = L_; p.bias = re_b; p.res = x; p.ldres = L_;
        gemm_bt<E_F32_BIAS_RES><<<gBig, blk, 0, stream>>>(p);
    }
    // ---- LN1 -> y ----
    ln_kernel<<<dim3(BC_), blk, 0, stream>>>(node, ln1g, ln1b, Yb);
    // ---- Q (scaled) + K + V(transposed) fused: Bt = Wt[1]||Wt[2]||Wt[3] ----
    {
        GemmP p{}; p.zmod = 1; p.K = L_;
        p.A = Yb; p.lda = L_; p.Bt = Wt[1]; p.ldb = L_;
        p.outB = Qb; p.outB2 = Kb; p.outB3 = VT;
        p.bias = bq; p.bias2 = bk; p.bias3 = bv; p.scale = 0.0625f;
        gemm_bt<E_QKV><<<gQKV, blk, 0, stream>>>(p);
    }
    // ---- S = q k^T per (b,h), bf16 logits ----
    {
        GemmP p{}; p.zmod = H_; p.K = 256;
        p.A = Qb;  p.lda = L_; p.sA1 = (long)C_ * L_; p.sA2 = 256;
        p.Bt = Kb; p.ldb = L_; p.sB1 = (long)C_ * L_; p.sB2 = 256;
        p.outB = Sbf; p.ldc = 256; p.sC1 = (long)H_ * 65536; p.sC2 = 65536;
        gemm_bt<E_BF16><<<gAttn, blk, 0, stream>>>(p);
    }
    // ---- softmax -> P (into RP; rank is dead) ----
    softmax_kernel<<<dim3(160 * 256 / 4), blk, 0, stream>>>(Sbf, RP);
    // ---- O = P V  (into Qb; q is dead) ----
    {
        GemmP p{}; p.zmod = H_; p.K = 256;
        p.A = RP;  p.lda = 256; p.sA1 = (long)H_ * 65536; p.sA2 = 65536;
        p.Bt = VT; p.ldb = 256; p.sB1 = (long)H_ * 65536; p.sB2 = 65536;
        p.outB = Qb; p.ldc = L_; p.sC1 = (long)C_ * L_; p.sC2 = 256;
        gemm_bt<E_BF16><<<gAttn, blk, 0, stream>>>(p);
    }
    // ---- h = node + O @ wo + bo (fp32, in place over node) ----
    {
        GemmP p{}; p.zmod = 1; p.K = L_;
        p.A = Qb; p.lda = L_; p.Bt = Wt[4]; p.ldb = L_;
        p.outF = node; p.ldc = L_; p.bias = bo; p.res = node; p.ldres = L_;
        gemm_bt<E_F32_BIAS_RES><<<gBig, blk, 0, stream>>>(p);
    }
    // ---- LN2 -> y2 (RP; P is dead) ----
    ln_kernel<<<dim3(BC_), blk, 0, stream>>>(node, ln2g, ln2b, RP);
    // ---- f1 = gelu(y2 @ w1 + b1) (Yb; y is dead) ----
    {
        GemmP p{}; p.zmod = 1; p.K = L_;
        p.A = RP; p.lda = L_; p.Bt = Wt[5]; p.ldb = L_;
        p.outB = Yb; p.ldc = L_; p.bias = fb1;
        gemm_bt<E_GELU><<<gBig, blk, 0, stream>>>(p);
    }
    // ---- h2 = h + f1 @ w2 + b2 -> transposed+padded (Kb; k is dead) ----
    zero_pads<<<dim3(64), blk, 0, stream>>>(Kb);
    {
        GemmP p{}; p.zmod = 1; p.K = L_;
        p.A = Yb; p.lda = L_; p.Bt = Wt[6]; p.ldb = L_;
        p.outB = Kb; p.bias = fb2; p.res = node; p.ldres = L_;
        gemm_bt<E_FFN2T><<<gBig, blk, 0, stream>>>(p);
    }
    // ---- conv: single fused K=768 GEMM + BN + ReLU ----
    {
        GemmP p{}; p.zmod = 1; p.K = 768;
        p.A = WconvT; p.lda = 768;                       // [co][t*256+ci]
        p.Bt = Kb; p.ldb = 256; p.sB1 = 1282 * 256;      // row lc reads h2T rows lc..lc+2
        p.outF = out; p.ldc = L_; p.sC1 = (long)C_ * L_;
        p.rowscale = bnscale; p.rowbias = bnbias;
        gemm_bt<E_CONVBNR><<<dim3(L_ / 128, 2, B_), blk, 0, stream>>>(p);
    }
}

// Round 11
// 541.886 us; speedup vs baseline: 1.3115x; 1.0227x over previous
//
#include <hip/hip_runtime.h>
#include <hip/hip_bf16.h>
#include <stdint.h>

// Problem constants
#define L_   1280
#define B_   32
#define C_   256
#define H_   5
#define D_   256
#define BC_  8192            // B_*C_
#define EPSV 1e-5f

typedef __attribute__((ext_vector_type(8))) short bf16x8;   // 8 bf16 (4 VGPRs)
typedef __attribute__((ext_vector_type(4))) float f32x4;    // 4 fp32 acc
typedef __hip_bfloat16 bf16;

__device__ __forceinline__ bf16 f2bf(float v) { return __float2bfloat16(v); }

// async global->LDS, 16B per lane; LDS dest is wave-uniform base + lane*16
#define GLDS16(gptr, lptr)                                                        \
    __builtin_amdgcn_global_load_lds(                                             \
        (const __attribute__((address_space(1))) void*)(gptr),                    \
        (__attribute__((address_space(3))) void*)(lptr), 16, 0, 0)

// ---------------------------------------------------------------------------
// Weight prep: fp32 [K,N] -> bf16 [N,K] (transposed) for 7 LxL matrices
// ---------------------------------------------------------------------------
struct WtArgs { const float* src[7]; bf16* dst[7]; };

__global__ __launch_bounds__(256) void transpose7(WtArgs a) {
    const int mat = blockIdx.z;
    const float* src = a.src[mat];
    bf16* dst = a.dst[mat];
    __shared__ float tile[32][33];
    const int bx = blockIdx.x * 32;   // n base
    const int by = blockIdx.y * 32;   // k base
    const int tx = threadIdx.x, ty = threadIdx.y;
    #pragma unroll
    for (int r = ty; r < 32; r += 8)
        tile[r][tx] = src[(size_t)(by + r) * L_ + bx + tx];
    __syncthreads();
    #pragma unroll
    for (int r = ty; r < 32; r += 8)
        dst[(size_t)(bx + r) * L_ + by + tx] = f2bf(tile[tx][r]);
}

// conv weight pack: conv_w[co][ci][t] -> WT[co][t*256+ci]  (K=768 fused layout)
// plus BN scale/bias
__global__ __launch_bounds__(256) void prep_conv(const float* cw, const float* g, const float* b,
                                                 const float* m, const float* v,
                                                 bf16* WT, float* sc, float* bi) {
    const int i = blockIdx.x * 256 + threadIdx.x;
    if (i < 3 * 256 * 256) {
        const int co = i / 768;
        const int r = i - co * 768;
        const int t = r >> 8, ci = r & 255;
        WT[i] = f2bf(cw[(co * 256 + ci) * 3 + t]);
    }
    if (i < 256) {
        const float s = g[i] * rsqrtf(v[i] + EPSV);
        sc[i] = s;
        bi[i] = b[i] - m[i] * s;
    }
}

// ---------------------------------------------------------------------------
// Rank kernel (bucket-histogram; eq-before term dropped, < 2e-5 effect)
// ---------------------------------------------------------------------------
__global__ __launch_bounds__(256) void rank_kernel(const float* __restrict__ x, bf16* __restrict__ R) {
    __shared__ float vals[L_];
    __shared__ float sv[L_];
    __shared__ int hist[256];
    __shared__ int pfx[256];
    __shared__ int cur[256];
    const int row = blockIdx.x, tid = threadIdx.x;
    const float* src = x + (size_t)row * L_;
    for (int i = tid; i < L_; i += 256) vals[i] = src[i];
    hist[tid] = 0;
    __syncthreads();
    float myv[5]; int myb[5];
    #pragma unroll
    for (int ii = 0; ii < 5; ii++) {
        const float v = vals[tid + ii * 256];
        int bk = (int)((4.0f - v) * 32.0f);
        bk = bk < 0 ? 0 : (bk > 255 ? 255 : bk);
        myv[ii] = v; myb[ii] = bk;
        atomicAdd(&hist[bk], 1);
    }
    __syncthreads();
    pfx[tid] = hist[tid];
    __syncthreads();
    for (int off = 1; off < 256; off <<= 1) {
        int t = (tid >= off) ? pfx[tid - off] : 0;
        __syncthreads();
        pfx[tid] += t;
        __syncthreads();
    }
    cur[tid] = pfx[tid] - hist[tid];
    __syncthreads();
    #pragma unroll
    for (int ii = 0; ii < 5; ii++) {
        const int pos = atomicAdd(&cur[myb[ii]], 1);
        sv[pos] = myv[ii];
    }
    __syncthreads();
    #pragma unroll
    for (int ii = 0; ii < 5; ii++) {
        const int bk = myb[ii]; const float v = myv[ii];
        const int s = pfx[bk] - hist[bk], e = pfx[bk];
        int cg = s;
        for (int p = s; p < e; p++) cg += (sv[p] > v) ? 1 : 0;
        R[(size_t)row * L_ + tid + ii * 256] = f2bf((float)(L_ - cg) * (1.0f / L_));
    }
}

// ---------------------------------------------------------------------------
// LayerNorm over last dim (1280), fp32 in -> bf16 out
// ---------------------------------------------------------------------------
__global__ __launch_bounds__(256) void ln_kernel(const float* __restrict__ in,
                                                 const float* __restrict__ g,
                                                 const float* __restrict__ b,
                                                 bf16* __restrict__ out) {
    const int row = blockIdx.x, tid = threadIdx.x;
    const float* src = in + (size_t)row * L_;
    float4 va = ((const float4*)src)[tid];
    float s = va.x + va.y + va.z + va.w;
    float ss = va.x * va.x + va.y * va.y + va.z * va.z + va.w * va.w;
    float4 vb = {0, 0, 0, 0};
    if (tid < 64) {
        vb = ((const float4*)src)[256 + tid];
        s += vb.x + vb.y + vb.z + vb.w;
        ss += vb.x * vb.x + vb.y * vb.y + vb.z * vb.z + vb.w * vb.w;
    }
    #pragma unroll
    for (int off = 32; off > 0; off >>= 1) {
        s += __shfl_down(s, off, 64);
        ss += __shfl_down(ss, off, 64);
    }
    __shared__ float rs[4], rss[4];
    __shared__ float mean_s, rstd_s;
    if ((tid & 63) == 0) { rs[tid >> 6] = s; rss[tid >> 6] = ss; }
    __syncthreads();
    if (tid == 0) {
        const float S = rs[0] + rs[1] + rs[2] + rs[3];
        const float SS = rss[0] + rss[1] + rss[2] + rss[3];
        const float m = S * (1.0f / L_);
        const float var = SS * (1.0f / L_) - m * m;
        mean_s = m; rstd_s = rsqrtf(var + EPSV);
    }
    __syncthreads();
    const float m = mean_s, r = rstd_s;
    {
        const int c = tid * 4;
        bf16 t4[4];
        t4[0] = f2bf((va.x - m) * r * g[c + 0] + b[c + 0]);
        t4[1] = f2bf((va.y - m) * r * g[c + 1] + b[c + 1]);
        t4[2] = f2bf((va.z - m) * r * g[c + 2] + b[c + 2]);
        t4[3] = f2bf((va.w - m) * r * g[c + 3] + b[c + 3]);
        *(uint2*)(out + (size_t)row * L_ + c) = *(uint2*)t4;
    }
    if (tid < 64) {
        const int c = 1024 + tid * 4;
        bf16 t4[4];
        t4[0] = f2bf((vb.x - m) * r * g[c + 0] + b[c + 0]);
        t4[1] = f2bf((vb.y - m) * r * g[c + 1] + b[c + 1]);
        t4[2] = f2bf((vb.z - m) * r * g[c + 2] + b[c + 2]);
        t4[3] = f2bf((vb.w - m) * r * g[c + 3] + b[c + 3]);
        *(uint2*)(out + (size_t)row * L_ + c) = *(uint2*)t4;
    }
}

// ---------------------------------------------------------------------------
// Row softmax: 256 bf16 logits -> 256 bf16 probs, one wave per row
// ---------------------------------------------------------------------------
__global__ __launch_bounds__(256) void softmax_kernel(const bf16* __restrict__ S, bf16* __restrict__ P) {
    const int row = blockIdx.x * 4 + (threadIdx.x >> 6);
    const int l = threadIdx.x & 63;
    const bf16* src = S + (size_t)row * 256 + l * 4;
    uint2 raw = *(const uint2*)src;
    bf16 s4[4]; *(uint2*)s4 = raw;
    float v0 = __bfloat162float(s4[0]), v1 = __bfloat162float(s4[1]);
    float v2 = __bfloat162float(s4[2]), v3 = __bfloat162float(s4[3]);
    float mx = fmaxf(fmaxf(v0, v1), fmaxf(v2, v3));
    #pragma unroll
    for (int off = 1; off < 64; off <<= 1) mx = fmaxf(mx, __shfl_xor(mx, off, 64));
    const float e0 = expf(v0 - mx), e1 = expf(v1 - mx), e2 = expf(v2 - mx), e3 = expf(v3 - mx);
    float sm = e0 + e1 + e2 + e3;
    #pragma unroll
    for (int off = 1; off < 64; off <<= 1) sm += __shfl_xor(sm, off, 64);
    const float inv = 1.0f / sm;
    bf16 t4[4] = { f2bf(e0 * inv), f2bf(e1 * inv), f2bf(e2 * inv), f2bf(e3 * inv) };
    *(uint2*)(P + (size_t)row * 256 + l * 4) = *(uint2*)t4;
}

// zero the two pad rows of h2Tpad [B][1282][256]
__global__ __launch_bounds__(256) void zero_pads(bf16* h2T) {
    const int i = blockIdx.x * 256 + threadIdx.x;   // 32*2*256 = 16384
    const int b = i >> 9;
    const int which = (i >> 8) & 1;
    const int ci = i & 255;
    const long row = which ? 1281 : 0;
    h2T[(long)b * (1282 * 256) + row * 256 + ci] = f2bf(0.0f);
}

// ---------------------------------------------------------------------------
// Generic batched GEMM: C[z][m][n] = sum_k A[z][m][k] * Bt[z][n][k]
// 128x128 tile, BK=32, 4 waves, mfma_f32_16x16x32_bf16.
// Counted-vmcnt 2-phase pipeline (T4); global_load_lds width=16 staging;
// XCD chunking with row-fastest order inside each chunk (B-tile L2 reuse).
// V-output blocks route the store through an LDS transpose (coalesced Vt).
// ---------------------------------------------------------------------------
struct GemmP {
    const bf16* A;  long lda, sA1, sA2;
    const bf16* Bt; long ldb, sB1, sB2;
    int zmod;
    int K;
    float* outF; bf16* outB; bf16* outB2; bf16* outB3; long ldc, sC1, sC2;
    const float* bias; const float* bias2; const float* bias3;
    const float* res; long ldres, sR1, sR2;
    const float* rowscale; const float* rowbias;
    float scale;
};

constexpr int E_F32_BIAS_RES = 0;  // outF = acc + bias[col] + res (outF may == res)
constexpr int E_F32 = 4;           // outF = acc       (with z offset)
constexpr int E_BF16 = 5;          // outB = bf16(acc) (with z offset)
constexpr int E_GELU = 6;          // outB = bf16(gelu(acc+bias))
constexpr int E_FFN2T = 7;         // h2 transposed+padded store
constexpr int E_CONVBNR = 8;       // relu(acc*rowscale+rowbias) -> outF
constexpr int E_QKV = 9;           // col<1280: Q*scale; <2560: K; else V via LDS-transpose

template <int EPI>
__global__ __launch_bounds__(256) void gemm_bt(GemmP p) {
    // ---- XCD chunking; row-fastest order within chunk ----
    const int nwg  = gridDim.x * gridDim.y * gridDim.z;
    const int orig = (blockIdx.z * gridDim.y + blockIdx.y) * gridDim.x + blockIdx.x;
    int bx, rowg;
    if ((nwg & 7) == 0) {
        const int chunk = nwg >> 3;
        const int xcd = orig & 7, pos = orig >> 3;
        const int rpc = chunk / gridDim.x;           // rows per chunk
        if (rpc * gridDim.x == chunk) {
            bx   = pos / rpc;                        // B-tile shared by rpc row-blocks
            rowg = xcd * rpc + (pos - bx * rpc);     // A-chunk stays L2-resident
        } else {
            const int wgid = xcd * chunk + pos;
            bx = wgid % gridDim.x; rowg = wgid / gridDim.x;
        }
    } else {
        bx = blockIdx.x; rowg = blockIdx.z * gridDim.y + blockIdx.y;
    }
    const int by = rowg % gridDim.y;
    const int bz = rowg / gridDim.y;

    const int zq = bz / p.zmod, zr = bz % p.zmod;
    const bf16* A  = p.A  + (long)zq * p.sA1 + (long)zr * p.sA2;
    const bf16* Bt = p.Bt + (long)zq * p.sB1 + (long)zr * p.sB2;
    const int row0 = by * 128, col0 = bx * 128;

    // 32 KB unified LDS: dbuf A (16K) + dbuf B (16K); reused whole as 128x128
    // bf16 transpose scratch in the V epilogue.
    __shared__ __align__(16) bf16 shm[16384];

    const int tid = threadIdx.x;
    const int l = tid & 63, w = tid >> 6;
    const int wr = w >> 1, wc = w & 1;

    f32x4 acc[4][4];
    #pragma unroll
    for (int m = 0; m < 4; m++)
        #pragma unroll
        for (int n = 0; n < 4; n++)
            acc[m][n] = (f32x4){0.f, 0.f, 0.f, 0.f};

    const bf16* gA = A  + (long)(row0 + w * 16 + (l >> 2)) * p.lda + (l & 3) * 8;
    const bf16* gB = Bt + (long)(col0 + w * 16 + (l >> 2)) * p.ldb + (l & 3) * 8;
    const long aStep = 64 * p.lda, bStep = 64 * p.ldb;

    auto STAGE = [&](int buf) {
        bf16* lA = shm + buf * 4096;
        bf16* lB = shm + 8192 + buf * 4096;
        GLDS16(gA,         lA + w * 512);
        GLDS16(gA + aStep, lA + 2048 + w * 512);
        GLDS16(gB,         lB + w * 512);
        GLDS16(gB + bStep, lB + 2048 + w * 512);
        gA += 32; gB += 32;
    };
    auto COMPUTE = [&](int buf) {
        const bf16* lA = shm + buf * 4096;
        const bf16* lB = shm + 8192 + buf * 4096;
        bf16x8 aF[4], bF[4];
        #pragma unroll
        for (int m = 0; m < 4; m++)
            aF[m] = *(const bf16x8*)(lA + (wr * 64 + m * 16 + (l & 15)) * 32 + (l >> 4) * 8);
        #pragma unroll
        for (int n = 0; n < 4; n++)
            bF[n] = *(const bf16x8*)(lB + (wc * 64 + n * 16 + (l & 15)) * 32 + (l >> 4) * 8);
        #pragma unroll
        for (int m = 0; m < 4; m++)
            #pragma unroll
            for (int n = 0; n < 4; n++)
                acc[m][n] = __builtin_amdgcn_mfma_f32_16x16x32_bf16(aF[m], bF[n], acc[m][n], 0, 0, 0);
    };

    // ---- counted-vmcnt 2-phase pipeline: never drain the just-issued stage ----
    const int nt = p.K >> 5;
    STAGE(0);
    int cur = 0;
    for (int t = 0; t < nt - 1; ++t) {
        STAGE(cur ^ 1);
        asm volatile("s_waitcnt vmcnt(4)" ::: "memory");   // only tile-t loads
        __builtin_amdgcn_sched_barrier(0);
        __builtin_amdgcn_s_barrier();
        COMPUTE(cur);
        __builtin_amdgcn_sched_barrier(0);
        __builtin_amdgcn_s_barrier();
        cur ^= 1;
    }
    asm volatile("s_waitcnt vmcnt(0)" ::: "memory");
    __builtin_amdgcn_sched_barrier(0);
    __builtin_amdgcn_s_barrier();
    COMPUTE(cur);

    // ---- V-block epilogue: LDS transpose -> coalesced 16B stores ----
    if constexpr (EPI == E_QKV) {
        if (col0 >= 2560) {
            const int v0  = col0 - 2560;
            const int hh  = v0 >> 8;
            const int dd0 = v0 & 255;          // 0 or 128
            const int b_  = row0 >> 8;
            const int c0b = row0 & 255;        // 0 or 128
            __syncthreads();                   // dbuf reads done; reuse shm
            #pragma unroll
            for (int m = 0; m < 4; m++)
                #pragma unroll
                for (int n = 0; n < 4; n++) {
                    const int cc = wc * 64 + n * 16 + (l & 15);   // local d
                    const float bb = p.bias3[v0 + cc];
                    #pragma unroll
                    for (int j = 0; j < 4; j++) {
                        const int r = wr * 64 + m * 16 + (l >> 4) * 4 + j;  // local c
                        shm[cc * 128 + (r ^ ((cc & 7) << 3))] = f2bf(acc[m][n][j] + bb);
                    }
                }
            __syncthreads();
            const int d = tid >> 1, ch = (tid & 1) * 64;
            bf16* dstRow = p.outB3 +
                (((long)((b_ * H_ + hh) * 256 + dd0 + d)) << 8) + c0b;
            #pragma unroll
            for (int g = 0; g < 8; g++) {
                const int rb = ch + g * 8;
                *(bf16x8*)(dstRow + rb) =
                    *(const bf16x8*)&shm[d * 128 + (rb ^ ((d & 7) << 3))];
            }
            return;
        }
    }

    const long cz = (long)zq * p.sC1 + (long)zr * p.sC2;
    const long rz = (long)zq * p.sR1 + (long)zr * p.sR2;
    #pragma unroll
    for (int m = 0; m < 4; m++) {
        #pragma unroll
        for (int n = 0; n < 4; n++) {
            const int gcol = col0 + wc * 64 + n * 16 + (l & 15);
            #pragma unroll
            for (int j = 0; j < 4; j++) {
                const int grow = row0 + wr * 64 + m * 16 + (l >> 4) * 4 + j;
                const float v = acc[m][n][j];
                if constexpr (EPI == E_F32_BIAS_RES) {
                    p.outF[cz + (long)grow * p.ldc + gcol] =
                        v + p.bias[gcol] + p.res[rz + (long)grow * p.ldres + gcol];
                } else if constexpr (EPI == E_F32) {
                    p.outF[cz + (long)grow * p.ldc + gcol] = v;
                } else if constexpr (EPI == E_BF16) {
                    p.outB[cz + (long)grow * p.ldc + gcol] = f2bf(v);
                } else if constexpr (EPI == E_GELU) {
                    const float t = v + p.bias[gcol];
                    p.outB[cz + (long)grow * p.ldc + gcol] =
                        f2bf(0.5f * t * (1.0f + erff(t * 0.70710678f)));
                } else if constexpr (EPI == E_FFN2T) {
                    const float t = v + p.bias[gcol] + p.res[rz + (long)grow * p.ldres + gcol];
                    const int b_ = grow >> 8, ci = grow & 255;
                    p.outB[(long)b_ * (1282 * 256) + (long)(gcol + 1) * 256 + ci] = f2bf(t);
                } else if constexpr (EPI == E_CONVBNR) {
                    const float t = v * p.rowscale[grow] + p.rowbias[grow];
                    p.outF[cz + (long)grow * p.ldc + gcol] = fmaxf(t, 0.0f);
                } else if constexpr (EPI == E_QKV) {
                    if (gcol < 1280) {                       // Q (scaled)
                        p.outB[(long)grow * L_ + gcol] = f2bf((v + p.bias[gcol]) * p.scale);
                    } else {                                 // K
                        const int c2 = gcol - 1280;
                        p.outB2[(long)grow * L_ + c2] = f2bf(v + p.bias2[c2]);
                    }
                }
            }
        }
    }
}

// ---------------------------------------------------------------------------
extern "C" void kernel_launch(void* const* d_in, const int* in_sizes, int n_in,
                              void* d_out, int out_size, void* d_ws, size_t ws_size,
                              hipStream_t stream) {
    const float* x    = (const float*)d_in[0];
    const float* re_w = (const float*)d_in[1];
    const float* re_b = (const float*)d_in[2];
    const float* ln1g = (const float*)d_in[3];
    const float* ln1b = (const float*)d_in[4];
    const float* ln2g = (const float*)d_in[5];
    const float* ln2b = (const float*)d_in[6];
    const float* wq   = (const float*)d_in[7];
    const float* bq   = (const float*)d_in[8];
    const float* wk   = (const float*)d_in[9];
    const float* bk   = (const float*)d_in[10];
    const float* wv   = (const float*)d_in[11];
    const float* bv   = (const float*)d_in[12];
    const float* wo   = (const float*)d_in[13];
    const float* bo   = (const float*)d_in[14];
    const float* fw1  = (const float*)d_in[15];
    const float* fb1  = (const float*)d_in[16];
    const float* fw2  = (const float*)d_in[17];
    const float* fb2  = (const float*)d_in[18];
    const float* convw = (const float*)d_in[19];
    const float* bng  = (const float*)d_in[20];
    const float* bnb  = (const float*)d_in[21];
    const float* bnm  = (const float*)d_in[22];
    const float* bnv  = (const float*)d_in[23];
    float* out = (float*)d_out;

    // ---- workspace layout (total 191,137,792 bytes) ----
    char* ws = (char*)d_ws;
    const size_t SZ_WT     = (size_t)L_ * L_ * 2;          // 3,276,800
    const size_t SZ_ACT_BF = (size_t)BC_ * L_ * 2;         // 20,971,520
    const size_t SZ_ACT_F  = (size_t)BC_ * L_ * 4;         // 41,943,040
    const size_t SZ_H2T    = (size_t)B_ * 1282 * 256 * 2;  // 21,004,288
    const size_t SZ_S      = (size_t)160 * 256 * 256 * 4;  // 41,943,040

    size_t off = 0;
    bf16* Wt[7];
    for (int i = 0; i < 7; i++) { Wt[i] = (bf16*)(ws + off); off += SZ_WT; }  // contiguous!
    bf16* WconvT   = (bf16*)(ws + off); off += 393216;
    float* bnscale = (float*)(ws + off); off += 1024;
    float* bnbias  = (float*)(ws + off); off += 1024;
    bf16* RP  = (bf16*)(ws + off); off += SZ_ACT_BF;  // rank -> P -> y2
    bf16* Yb  = (bf16*)(ws + off); off += SZ_ACT_BF;  // y -> f1
    bf16* Qb  = (bf16*)(ws + off); off += SZ_ACT_BF;  // q -> attn O
    bf16* Kb  = (bf16*)(ws + off); off += SZ_H2T;     // k -> h2Tpad
    float* Sb = (float*)(ws + off); off += SZ_S;      // [Sbf16 21MB][VT 21MB]
    float* node = (float*)(ws + off); off += SZ_ACT_F; // node -> h (in place)
    bf16* Sbf = (bf16*)Sb;                             // bf16 scores, first half
    bf16* VT  = Sbf + (size_t)160 * 65536;             // V^T, second half
    (void)in_sizes; (void)n_in; (void)out_size;

    // Diagnostic guard: if ws is too small, fail cleanly (absmax ~8.5, no fault)
    if (ws_size < off) return;

    // ---- weight prep ----
    WtArgs wa;
    wa.src[0] = re_w; wa.src[1] = wq; wa.src[2] = wk; wa.src[3] = wv;
    wa.src[4] = wo;  wa.src[5] = fw1; wa.src[6] = fw2;
    for (int i = 0; i < 7; i++) wa.dst[i] = Wt[i];
    transpose7<<<dim3(40, 40, 7), dim3(32, 8), 0, stream>>>(wa);
    prep_conv<<<dim3(768), 256, 0, stream>>>(convw, bng, bnb, bnm, bnv, WconvT, bnscale, bnbias);

    // ---- rank ----
    rank_kernel<<<dim3(BC_), 256, 0, stream>>>(x, RP);

    const dim3 gBig(L_ / 128, BC_ / 128, 1);      // (10, 64)
    const dim3 gQKV(3840 / 128, BC_ / 128, 1);    // (30, 64)
    const dim3 gAttn(2, 2, 160);
    const dim3 blk(256);

    // ---- node = x + rank @ re_w + re_b (fp32) ----
    {
        GemmP p{}; p.zmod = 1; p.K = L_;
        p.A = RP; p.lda = L_; p.Bt = Wt[0]; p.ldb = L_;
        p.outF = node; p.ldc = L_; p.bias = re_b; p.res = x; p.ldres = L_;
        gemm_bt<E_F32_BIAS_RES><<<gBig, blk, 0, stream>>>(p);
    }
    // ---- LN1 -> y ----
    ln_kernel<<<dim3(BC_), blk, 0, stream>>>(node, ln1g, ln1b, Yb);
    // ---- Q (scaled) + K + V(transposed) fused: Bt = Wt[1]||Wt[2]||Wt[3] ----
    {
        GemmP p{}; p.zmod = 1; p.K = L_;
        p.A = Yb; p.lda = L_; p.Bt = Wt[1]; p.ldb = L_;
        p.outB = Qb; p.outB2 = Kb; p.outB3 = VT;
        p.bias = bq; p.bias2 = bk; p.bias3 = bv; p.scale = 0.0625f;
        gemm_bt<E_QKV><<<gQKV, blk, 0, stream>>>(p);
    }
    // ---- S = q k^T per (b,h), bf16 logits ----
    {
        GemmP p{}; p.zmod = H_; p.K = 256;
        p.A = Qb;  p.lda = L_; p.sA1 = (long)C_ * L_; p.sA2 = 256;
        p.Bt = Kb; p.ldb = L_; p.sB1 = (long)C_ * L_; p.sB2 = 256;
        p.outB = Sbf; p.ldc = 256; p.sC1 = (long)H_ * 65536; p.sC2 = 65536;
        gemm_bt<E_BF16><<<gAttn, blk, 0, stream>>>(p);
    }
    // ---- softmax -> P (into RP; rank is dead) ----
    softmax_kernel<<<dim3(160 * 256 / 4), blk, 0, stream>>>(Sbf, RP);
    // ---- O = P V  (into Qb; q is dead) ----
    {
        GemmP p{}; p.zmod = H_; p.K = 256;
        p.A = RP;  p.lda = 256; p.sA1 = (long)H_ * 65536; p.sA2 = 65536;
        p.Bt = VT; p.ldb = 256; p.sB1 = (long)H_ * 65536; p.sB2 = 65536;
        p.outB = Qb; p.ldc = L_; p.sC1 = (long)C_ * L_; p.sC2 = 256;
        gemm_bt<E_BF16><<<gAttn, blk, 0, stream>>>(p);
    }
    // ---- h = node + O @ wo + bo (fp32, in place over node) ----
    {
        GemmP p{}; p.zmod = 1; p.K = L_;
        p.A = Qb; p.lda = L_; p.Bt = Wt[4]; p.ldb = L_;
        p.outF = node; p.ldc = L_; p.bias = bo; p.res = node; p.ldres = L_;
        gemm_bt<E_F32_BIAS_RES><<<gBig, blk, 0, stream>>>(p);
    }
    // ---- LN2 -> y2 (RP; P is dead) ----
    ln_kernel<<<dim3(BC_), blk, 0, stream>>>(node, ln2g, ln2b, RP);
    // ---- f1 = gelu(y2 @ w1 + b1) (Yb; y is dead) ----
    {
        GemmP p{}; p.zmod = 1; p.K = L_;
        p.A = RP; p.lda = L_; p.Bt = Wt[5]; p.ldb = L_;
        p.outB = Yb; p.ldc = L_; p.bias = fb1;
        gemm_bt<E_GELU><<<gBig, blk, 0, stream>>>(p);
    }
    // ---- h2 = h + f1 @ w2 + b2 -> transposed+padded (Kb; k is dead) ----
    zero_pads<<<dim3(64), blk, 0, stream>>>(Kb);
    {
        GemmP p{}; p.zmod = 1; p.K = L_;
        p.A = Yb; p.lda = L_; p.Bt = Wt[6]; p.ldb = L_;
        p.outB = Kb; p.bias = fb2; p.res = node; p.ldres = L_;
        gemm_bt<E_FFN2T><<<gBig, blk, 0, stream>>>(p);
    }
    // ---- conv: single fused K=768 GEMM + BN + ReLU ----
    {
        GemmP p{}; p.zmod = 1; p.K = 768;
        p.A = WconvT; p.lda = 768;                       // [co][t*256+ci]
        p.Bt = Kb; p.ldb = 256; p.sB1 = 1282 * 256;      // row lc reads h2T rows lc..lc+2
        p.outF = out; p.ldc = L_; p.sC1 = (long)C_ * L_;
        p.rowscale = bnscale; p.rowbias = bnbias;
        gemm_bt<E_CONVBNR><<<dim3(L_ / 128, 2, B_), blk, 0, stream>>>(p);
    }
}

// Round 12
// 520.366 us; speedup vs baseline: 1.3658x; 1.0414x over previous
//
#include <hip/hip_runtime.h>
#include <hip/hip_bf16.h>
#include <stdint.h>

// Problem constants
#define L_   1280
#define B_   32
#define C_   256
#define H_   5
#define D_   256
#define BC_  8192            // B_*C_
#define EPSV 1e-5f

typedef __attribute__((ext_vector_type(8))) short bf16x8;   // 8 bf16 (4 VGPRs)
typedef __attribute__((ext_vector_type(4))) float f32x4;    // 4 fp32 acc
typedef __hip_bfloat16 bf16;

__device__ __forceinline__ bf16 f2bf(float v) { return __float2bfloat16(v); }
__device__ __forceinline__ float bf2f(bf16 v) { return __bfloat162float(v); }

// async global->LDS, 16B per lane; LDS dest is wave-uniform base + lane*16
#define GLDS16(gptr, lptr)                                                        \
    __builtin_amdgcn_global_load_lds(                                             \
        (const __attribute__((address_space(1))) void*)(gptr),                    \
        (__attribute__((address_space(3))) void*)(lptr), 16, 0, 0)

// ---------------------------------------------------------------------------
// Weight prep: fp32 [K,N] -> bf16 [N,K] (transposed) for 7 LxL matrices
// ---------------------------------------------------------------------------
struct WtArgs { const float* src[7]; bf16* dst[7]; };

__global__ __launch_bounds__(256) void transpose7(WtArgs a) {
    const int mat = blockIdx.z;
    const float* src = a.src[mat];
    bf16* dst = a.dst[mat];
    __shared__ float tile[32][33];
    const int bx = blockIdx.x * 32;   // n base
    const int by = blockIdx.y * 32;   // k base
    const int tx = threadIdx.x, ty = threadIdx.y;
    #pragma unroll
    for (int r = ty; r < 32; r += 8)
        tile[r][tx] = src[(size_t)(by + r) * L_ + bx + tx];
    __syncthreads();
    #pragma unroll
    for (int r = ty; r < 32; r += 8)
        dst[(size_t)(bx + r) * L_ + by + tx] = f2bf(tile[tx][r]);
}

// conv weight pack: conv_w[co][ci][t] -> WT[co][t*256+ci]  (K=768 fused layout)
// plus BN scale/bias
__global__ __launch_bounds__(256) void prep_conv(const float* cw, const float* g, const float* b,
                                                 const float* m, const float* v,
                                                 bf16* WT, float* sc, float* bi) {
    const int i = blockIdx.x * 256 + threadIdx.x;
    if (i < 3 * 256 * 256) {
        const int co = i / 768;
        const int r = i - co * 768;
        const int t = r >> 8, ci = r & 255;
        WT[i] = f2bf(cw[(co * 256 + ci) * 3 + t]);
    }
    if (i < 256) {
        const float s = g[i] * rsqrtf(v[i] + EPSV);
        sc[i] = s;
        bi[i] = b[i] - m[i] * s;
    }
}

// ---------------------------------------------------------------------------
// Rank kernel (bucket-histogram; eq-before term dropped, < 2e-5 effect)
// ---------------------------------------------------------------------------
__global__ __launch_bounds__(256) void rank_kernel(const float* __restrict__ x, bf16* __restrict__ R) {
    __shared__ float vals[L_];
    __shared__ float sv[L_];
    __shared__ int hist[256];
    __shared__ int pfx[256];
    __shared__ int cur[256];
    const int row = blockIdx.x, tid = threadIdx.x;
    const float* src = x + (size_t)row * L_;
    for (int i = tid; i < L_; i += 256) vals[i] = src[i];
    hist[tid] = 0;
    __syncthreads();
    float myv[5]; int myb[5];
    #pragma unroll
    for (int ii = 0; ii < 5; ii++) {
        const float v = vals[tid + ii * 256];
        int bk = (int)((4.0f - v) * 32.0f);
        bk = bk < 0 ? 0 : (bk > 255 ? 255 : bk);
        myv[ii] = v; myb[ii] = bk;
        atomicAdd(&hist[bk], 1);
    }
    __syncthreads();
    pfx[tid] = hist[tid];
    __syncthreads();
    for (int off = 1; off < 256; off <<= 1) {
        int t = (tid >= off) ? pfx[tid - off] : 0;
        __syncthreads();
        pfx[tid] += t;
        __syncthreads();
    }
    cur[tid] = pfx[tid] - hist[tid];
    __syncthreads();
    #pragma unroll
    for (int ii = 0; ii < 5; ii++) {
        const int pos = atomicAdd(&cur[myb[ii]], 1);
        sv[pos] = myv[ii];
    }
    __syncthreads();
    #pragma unroll
    for (int ii = 0; ii < 5; ii++) {
        const int bk = myb[ii]; const float v = myv[ii];
        const int s = pfx[bk] - hist[bk], e = pfx[bk];
        int cg = s;
        for (int p = s; p < e; p++) cg += (sv[p] > v) ? 1 : 0;
        R[(size_t)row * L_ + tid + ii * 256] = f2bf((float)(L_ - cg) * (1.0f / L_));
    }
}

// ---------------------------------------------------------------------------
// LayerNorm over last dim (1280), bf16 in -> bf16 out
// ---------------------------------------------------------------------------
__global__ __launch_bounds__(256) void ln_kernel(const bf16* __restrict__ in,
                                                 const float* __restrict__ g,
                                                 const float* __restrict__ b,
                                                 bf16* __restrict__ out) {
    const int row = blockIdx.x, tid = threadIdx.x;
    const bf16* src = in + (size_t)row * L_;
    uint2 ra = ((const uint2*)src)[tid];
    bf16 a4[4]; *(uint2*)a4 = ra;
    const float a0 = bf2f(a4[0]), a1 = bf2f(a4[1]), a2 = bf2f(a4[2]), a3 = bf2f(a4[3]);
    float s = a0 + a1 + a2 + a3;
    float ss = a0 * a0 + a1 * a1 + a2 * a2 + a3 * a3;
    float b0 = 0, b1 = 0, b2 = 0, b3 = 0;
    if (tid < 64) {
        uint2 rb = ((const uint2*)src)[256 + tid];
        bf16 b4[4]; *(uint2*)b4 = rb;
        b0 = bf2f(b4[0]); b1 = bf2f(b4[1]); b2 = bf2f(b4[2]); b3 = bf2f(b4[3]);
        s += b0 + b1 + b2 + b3;
        ss += b0 * b0 + b1 * b1 + b2 * b2 + b3 * b3;
    }
    #pragma unroll
    for (int off = 32; off > 0; off >>= 1) {
        s += __shfl_down(s, off, 64);
        ss += __shfl_down(ss, off, 64);
    }
    __shared__ float rs[4], rss[4];
    __shared__ float mean_s, rstd_s;
    if ((tid & 63) == 0) { rs[tid >> 6] = s; rss[tid >> 6] = ss; }
    __syncthreads();
    if (tid == 0) {
        const float S = rs[0] + rs[1] + rs[2] + rs[3];
        const float SS = rss[0] + rss[1] + rss[2] + rss[3];
        const float m = S * (1.0f / L_);
        const float var = SS * (1.0f / L_) - m * m;
        mean_s = m; rstd_s = rsqrtf(var + EPSV);
    }
    __syncthreads();
    const float m = mean_s, r = rstd_s;
    {
        const int c = tid * 4;
        bf16 t4[4];
        t4[0] = f2bf((a0 - m) * r * g[c + 0] + b[c + 0]);
        t4[1] = f2bf((a1 - m) * r * g[c + 1] + b[c + 1]);
        t4[2] = f2bf((a2 - m) * r * g[c + 2] + b[c + 2]);
        t4[3] = f2bf((a3 - m) * r * g[c + 3] + b[c + 3]);
        *(uint2*)(out + (size_t)row * L_ + c) = *(uint2*)t4;
    }
    if (tid < 64) {
        const int c = 1024 + tid * 4;
        bf16 t4[4];
        t4[0] = f2bf((b0 - m) * r * g[c + 0] + b[c + 0]);
        t4[1] = f2bf((b1 - m) * r * g[c + 1] + b[c + 1]);
        t4[2] = f2bf((b2 - m) * r * g[c + 2] + b[c + 2]);
        t4[3] = f2bf((b3 - m) * r * g[c + 3] + b[c + 3]);
        *(uint2*)(out + (size_t)row * L_ + c) = *(uint2*)t4;
    }
}

// ---------------------------------------------------------------------------
// Row softmax: 256 bf16 logits -> 256 bf16 probs, one wave per row
// ---------------------------------------------------------------------------
__global__ __launch_bounds__(256) void softmax_kernel(const bf16* __restrict__ S, bf16* __restrict__ P) {
    const int row = blockIdx.x * 4 + (threadIdx.x >> 6);
    const int l = threadIdx.x & 63;
    const bf16* src = S + (size_t)row * 256 + l * 4;
    uint2 raw = *(const uint2*)src;
    bf16 s4[4]; *(uint2*)s4 = raw;
    float v0 = bf2f(s4[0]), v1 = bf2f(s4[1]);
    float v2 = bf2f(s4[2]), v3 = bf2f(s4[3]);
    float mx = fmaxf(fmaxf(v0, v1), fmaxf(v2, v3));
    #pragma unroll
    for (int off = 1; off < 64; off <<= 1) mx = fmaxf(mx, __shfl_xor(mx, off, 64));
    const float e0 = expf(v0 - mx), e1 = expf(v1 - mx), e2 = expf(v2 - mx), e3 = expf(v3 - mx);
    float sm = e0 + e1 + e2 + e3;
    #pragma unroll
    for (int off = 1; off < 64; off <<= 1) sm += __shfl_xor(sm, off, 64);
    const float inv = 1.0f / sm;
    bf16 t4[4] = { f2bf(e0 * inv), f2bf(e1 * inv), f2bf(e2 * inv), f2bf(e3 * inv) };
    *(uint2*)(P + (size_t)row * 256 + l * 4) = *(uint2*)t4;
}

// zero the two pad rows of h2Tpad [B][1282][256]
__global__ __launch_bounds__(256) void zero_pads(bf16* h2T) {
    const int i = blockIdx.x * 256 + threadIdx.x;   // 32*2*256 = 16384
    const int b = i >> 9;
    const int which = (i >> 8) & 1;
    const int ci = i & 255;
    const long row = which ? 1281 : 0;
    h2T[(long)b * (1282 * 256) + row * 256 + ci] = f2bf(0.0f);
}

// ---------------------------------------------------------------------------
// Generic batched GEMM: C[z][m][n] = sum_k A[z][m][k] * Bt[z][n][k]
// 128x128 tile, BK=32, 4 waves, mfma_f32_16x16x32_bf16.
// 3-buffer rotation, ONE barrier + counted vmcnt(4) per K-step (T3/T4):
// tile t+2 staged right after the iter-t barrier; buffer (t+2)%3 was last
// read in COMPUTE(t-1), which precedes the barrier for every wave -> safe.
// XCD chunking with row-fastest order inside each chunk (B-tile L2 reuse).
// V-output blocks route the store through an LDS transpose (coalesced Vt).
// ---------------------------------------------------------------------------
struct GemmP {
    const bf16* A;  long lda, sA1, sA2;
    const bf16* Bt; long ldb, sB1, sB2;
    int zmod;
    int K;
    float* outF; bf16* outB; bf16* outB2; bf16* outB3; long ldc, sC1, sC2;
    const float* bias; const float* bias2; const float* bias3;
    const float* res; const bf16* resB; long ldres, sR1, sR2;
    const float* rowscale; const float* rowbias;
    float scale;
};

constexpr int E_NODE = 0;          // outB = bf16(acc + bias + resF32)    (node = x + ...)
constexpr int E_HRES = 1;          // outB = bf16(acc + bias + f(resB))   (h, in-place)
constexpr int E_BF16 = 5;          // outB = bf16(acc) (with z offset)
constexpr int E_GELU = 6;          // outB = bf16(gelu(acc+bias))
constexpr int E_FFN2T = 7;         // h2 transposed+padded store (bf16 res)
constexpr int E_CONVBNR = 8;       // relu(acc*rowscale+rowbias) -> outF
constexpr int E_QKV = 9;           // col<1280: Q*scale; <2560: K; else V via LDS-transpose

template <int EPI>
__global__ __launch_bounds__(256) void gemm_bt(GemmP p) {
    // ---- XCD chunking; row-fastest order within chunk ----
    const int nwg  = gridDim.x * gridDim.y * gridDim.z;
    const int orig = (blockIdx.z * gridDim.y + blockIdx.y) * gridDim.x + blockIdx.x;
    int bx, rowg;
    if ((nwg & 7) == 0) {
        const int chunk = nwg >> 3;
        const int xcd = orig & 7, pos = orig >> 3;
        const int rpc = chunk / gridDim.x;           // rows per chunk
        if (rpc * gridDim.x == chunk) {
            bx   = pos / rpc;                        // B-tile shared by rpc row-blocks
            rowg = xcd * rpc + (pos - bx * rpc);     // A-chunk stays L2-resident
        } else {
            const int wgid = xcd * chunk + pos;
            bx = wgid % gridDim.x; rowg = wgid / gridDim.x;
        }
    } else {
        bx = blockIdx.x; rowg = blockIdx.z * gridDim.y + blockIdx.y;
    }
    const int by = rowg % gridDim.y;
    const int bz = rowg / gridDim.y;

    const int zq = bz / p.zmod, zr = bz % p.zmod;
    const bf16* A  = p.A  + (long)zq * p.sA1 + (long)zr * p.sA2;
    const bf16* Bt = p.Bt + (long)zq * p.sB1 + (long)zr * p.sB2;
    const int row0 = by * 128, col0 = bx * 128;

    // 48 KB LDS: 3 x (A 8K + B 8K); reused whole as 128x128 bf16 transpose
    // scratch in the V epilogue.
    __shared__ __align__(16) bf16 shm[24576];

    const int tid = threadIdx.x;
    const int l = tid & 63, w = tid >> 6;
    const int wr = w >> 1, wc = w & 1;

    f32x4 acc[4][4];
    #pragma unroll
    for (int m = 0; m < 4; m++)
        #pragma unroll
        for (int n = 0; n < 4; n++)
            acc[m][n] = (f32x4){0.f, 0.f, 0.f, 0.f};

    const bf16* gA = A  + (long)(row0 + w * 16 + (l >> 2)) * p.lda + (l & 3) * 8;
    const bf16* gB = Bt + (long)(col0 + w * 16 + (l >> 2)) * p.ldb + (l & 3) * 8;
    const long aStep = 64 * p.lda, bStep = 64 * p.ldb;

    auto STAGE = [&](int buf) {
        bf16* lA = shm + buf * 4096;
        bf16* lB = shm + 12288 + buf * 4096;
        GLDS16(gA,         lA + w * 512);
        GLDS16(gA + aStep, lA + 2048 + w * 512);
        GLDS16(gB,         lB + w * 512);
        GLDS16(gB + bStep, lB + 2048 + w * 512);
        gA += 32; gB += 32;
    };
    auto COMPUTE = [&](int buf) {
        const bf16* lA = shm + buf * 4096;
        const bf16* lB = shm + 12288 + buf * 4096;
        bf16x8 aF[4], bF[4];
        #pragma unroll
        for (int m = 0; m < 4; m++)
            aF[m] = *(const bf16x8*)(lA + (wr * 64 + m * 16 + (l & 15)) * 32 + (l >> 4) * 8);
        #pragma unroll
        for (int n = 0; n < 4; n++)
            bF[n] = *(const bf16x8*)(lB + (wc * 64 + n * 16 + (l & 15)) * 32 + (l >> 4) * 8);
        #pragma unroll
        for (int m = 0; m < 4; m++)
            #pragma unroll
            for (int n = 0; n < 4; n++)
                acc[m][n] = __builtin_amdgcn_mfma_f32_16x16x32_bf16(aF[m], bF[n], acc[m][n], 0, 0, 0);
    };

    // ---- 3-buffer rotation: 1 barrier + counted vmcnt per K-step ----
    const int nt = p.K >> 5;          // nt >= 8 for all our shapes
    STAGE(0); STAGE(1);               // tiles 0,1 in flight (8 loads/wave)
    int cb = 0, sb = 2;
    for (int t = 0; t < nt - 1; ++t) {
        asm volatile("s_waitcnt vmcnt(4)" ::: "memory");   // retire tile t only
        __builtin_amdgcn_sched_barrier(0);
        __builtin_amdgcn_s_barrier();                      // buf[cb] ready; buf[sb] free
        if (t + 2 < nt) STAGE(sb);                         // tile t+2 in flight
        COMPUTE(cb);
        cb = (cb == 2) ? 0 : cb + 1;
        sb = (sb == 2) ? 0 : sb + 1;
    }
    asm volatile("s_waitcnt vmcnt(0)" ::: "memory");
    __builtin_amdgcn_sched_barrier(0);
    __builtin_amdgcn_s_barrier();
    COMPUTE(cb);                                           // last tile

    // ---- V-block epilogue: LDS transpose -> coalesced 16B stores ----
    if constexpr (EPI == E_QKV) {
        if (col0 >= 2560) {
            const int v0  = col0 - 2560;
            const int hh  = v0 >> 8;
            const int dd0 = v0 & 255;          // 0 or 128
            const int b_  = row0 >> 8;
            const int c0b = row0 & 255;        // 0 or 128
            __syncthreads();                   // pipeline LDS reads done; reuse shm
            #pragma unroll
            for (int m = 0; m < 4; m++)
                #pragma unroll
                for (int n = 0; n < 4; n++) {
                    const int cc = wc * 64 + n * 16 + (l & 15);   // local d
                    const float bb = p.bias3[v0 + cc];
                    #pragma unroll
                    for (int j = 0; j < 4; j++) {
                        const int r = wr * 64 + m * 16 + (l >> 4) * 4 + j;  // local c
                        shm[cc * 128 + (r ^ ((cc & 7) << 3))] = f2bf(acc[m][n][j] + bb);
                    }
                }
            __syncthreads();
            const int d = tid >> 1, ch = (tid & 1) * 64;
            bf16* dstRow = p.outB3 +
                (((long)((b_ * H_ + hh) * 256 + dd0 + d)) << 8) + c0b;
            #pragma unroll
            for (int g = 0; g < 8; g++) {
                const int rb = ch + g * 8;
                *(bf16x8*)(dstRow + rb) =
                    *(const bf16x8*)&shm[d * 128 + (rb ^ ((d & 7) << 3))];
            }
            return;
        }
    }

    const long cz = (long)zq * p.sC1 + (long)zr * p.sC2;
    const long rz = (long)zq * p.sR1 + (long)zr * p.sR2;
    #pragma unroll
    for (int m = 0; m < 4; m++) {
        #pragma unroll
        for (int n = 0; n < 4; n++) {
            const int gcol = col0 + wc * 64 + n * 16 + (l & 15);
            #pragma unroll
            for (int j = 0; j < 4; j++) {
                const int grow = row0 + wr * 64 + m * 16 + (l >> 4) * 4 + j;
                const float v = acc[m][n][j];
                if constexpr (EPI == E_NODE) {
                    p.outB[cz + (long)grow * p.ldc + gcol] =
                        f2bf(v + p.bias[gcol] + p.res[rz + (long)grow * p.ldres + gcol]);
                } else if constexpr (EPI == E_HRES) {
                    p.outB[cz + (long)grow * p.ldc + gcol] =
                        f2bf(v + p.bias[gcol] + bf2f(p.resB[rz + (long)grow * p.ldres + gcol]));
                } else if constexpr (EPI == E_BF16) {
                    p.outB[cz + (long)grow * p.ldc + gcol] = f2bf(v);
                } else if constexpr (EPI == E_GELU) {
                    const float t = v + p.bias[gcol];
                    p.outB[cz + (long)grow * p.ldc + gcol] =
                        f2bf(0.5f * t * (1.0f + erff(t * 0.70710678f)));
                } else if constexpr (EPI == E_FFN2T) {
                    const float t = v + p.bias[gcol] +
                                    bf2f(p.resB[rz + (long)grow * p.ldres + gcol]);
                    const int b_ = grow >> 8, ci = grow & 255;
                    p.outB[(long)b_ * (1282 * 256) + (long)(gcol + 1) * 256 + ci] = f2bf(t);
                } else if constexpr (EPI == E_CONVBNR) {
                    const float t = v * p.rowscale[grow] + p.rowbias[grow];
                    p.outF[cz + (long)grow * p.ldc + gcol] = fmaxf(t, 0.0f);
                } else if constexpr (EPI == E_QKV) {
                    if (gcol < 1280) {                       // Q (scaled)
                        p.outB[(long)grow * L_ + gcol] = f2bf((v + p.bias[gcol]) * p.scale);
                    } else {                                 // K
                        const int c2 = gcol - 1280;
                        p.outB2[(long)grow * L_ + c2] = f2bf(v + p.bias2[c2]);
                    }
                }
            }
        }
    }
}

// ---------------------------------------------------------------------------
extern "C" void kernel_launch(void* const* d_in, const int* in_sizes, int n_in,
                              void* d_out, int out_size, void* d_ws, size_t ws_size,
                              hipStream_t stream) {
    const float* x    = (const float*)d_in[0];
    const float* re_w = (const float*)d_in[1];
    const float* re_b = (const float*)d_in[2];
    const float* ln1g = (const float*)d_in[3];
    const float* ln1b = (const float*)d_in[4];
    const float* ln2g = (const float*)d_in[5];
    const float* ln2b = (const float*)d_in[6];
    const float* wq   = (const float*)d_in[7];
    const float* bq   = (const float*)d_in[8];
    const float* wk   = (const float*)d_in[9];
    const float* bk   = (const float*)d_in[10];
    const float* wv   = (const float*)d_in[11];
    const float* bv   = (const float*)d_in[12];
    const float* wo   = (const float*)d_in[13];
    const float* bo   = (const float*)d_in[14];
    const float* fw1  = (const float*)d_in[15];
    const float* fb1  = (const float*)d_in[16];
    const float* fw2  = (const float*)d_in[17];
    const float* fb2  = (const float*)d_in[18];
    const float* convw = (const float*)d_in[19];
    const float* bng  = (const float*)d_in[20];
    const float* bnb  = (const float*)d_in[21];
    const float* bnm  = (const float*)d_in[22];
    const float* bnv  = (const float*)d_in[23];
    float* out = (float*)d_out;

    // ---- workspace layout (total ~170 MB) ----
    char* ws = (char*)d_ws;
    const size_t SZ_WT     = (size_t)L_ * L_ * 2;          // 3,276,800
    const size_t SZ_ACT_BF = (size_t)BC_ * L_ * 2;         // 20,971,520
    const size_t SZ_H2T    = (size_t)B_ * 1282 * 256 * 2;  // 21,004,288
    const size_t SZ_S      = (size_t)160 * 256 * 256 * 4;  // 41,943,040

    size_t off = 0;
    bf16* Wt[7];
    for (int i = 0; i < 7; i++) { Wt[i] = (bf16*)(ws + off); off += SZ_WT; }  // contiguous!
    bf16* WconvT   = (bf16*)(ws + off); off += 393216;
    float* bnscale = (float*)(ws + off); off += 1024;
    float* bnbias  = (float*)(ws + off); off += 1024;
    bf16* RP  = (bf16*)(ws + off); off += SZ_ACT_BF;  // rank -> P -> y2
    bf16* Yb  = (bf16*)(ws + off); off += SZ_ACT_BF;  // y -> f1
    bf16* Qb  = (bf16*)(ws + off); off += SZ_ACT_BF;  // q -> attn O
    bf16* Kb  = (bf16*)(ws + off); off += SZ_H2T;     // k -> h2Tpad
    float* Sb = (float*)(ws + off); off += SZ_S;      // [Sbf16 21MB][VT 21MB]
    bf16* nodeB = (bf16*)(ws + off); off += SZ_ACT_BF; // node -> h (bf16, in place)
    bf16* Sbf = (bf16*)Sb;                             // bf16 scores, first half
    bf16* VT  = Sbf + (size_t)160 * 65536;             // V^T, second half
    (void)in_sizes; (void)n_in; (void)out_size;

    // Diagnostic guard: if ws is too small, fail cleanly (absmax ~8.5, no fault)
    if (ws_size < off) return;

    // ---- weight prep ----
    WtArgs wa;
    wa.src[0] = re_w; wa.src[1] = wq; wa.src[2] = wk; wa.src[3] = wv;
    wa.src[4] = wo;  wa.src[5] = fw1; wa.src[6] = fw2;
    for (int i = 0; i < 7; i++) wa.dst[i] = Wt[i];
    transpose7<<<dim3(40, 40, 7), dim3(32, 8), 0, stream>>>(wa);
    prep_conv<<<dim3(768), 256, 0, stream>>>(convw, bng, bnb, bnm, bnv, WconvT, bnscale, bnbias);

    // ---- rank ----
    rank_kernel<<<dim3(BC_), 256, 0, stream>>>(x, RP);

    const dim3 gBig(L_ / 128, BC_ / 128, 1);      // (10, 64)
    const dim3 gQKV(3840 / 128, BC_ / 128, 1);    // (30, 64)
    const dim3 gAttn(2, 2, 160);
    const dim3 blk(256);

    // ---- node = bf16(x + rank @ re_w + re_b) ----
    {
        GemmP p{}; p.zmod = 1; p.K = L_;
        p.A = RP; p.lda = L_; p.Bt = Wt[0]; p.ldb = L_;
        p.outB = nodeB; p.ldc = L_; p.bias = re_b; p.res = x; p.ldres = L_;
        gemm_bt<E_NODE><<<gBig, blk, 0, stream>>>(p);
    }
    // ---- LN1 -> y ----
    ln_kernel<<<dim3(BC_), blk, 0, stream>>>(nodeB, ln1g, ln1b, Yb);
    // ---- Q (scaled) + K + V(transposed) fused: Bt = Wt[1]||Wt[2]||Wt[3] ----
    {
        GemmP p{}; p.zmod = 1; p.K = L_;
        p.A = Yb; p.lda = L_; p.Bt = Wt[1]; p.ldb = L_;
        p.outB = Qb; p.outB2 = Kb; p.outB3 = VT;
        p.bias = bq; p.bias2 = bk; p.bias3 = bv; p.scale = 0.0625f;
        gemm_bt<E_QKV><<<gQKV, blk, 0, stream>>>(p);
    }
    // ---- S = q k^T per (b,h), bf16 logits ----
    {
        GemmP p{}; p.zmod = H_; p.K = 256;
        p.A = Qb;  p.lda = L_; p.sA1 = (long)C_ * L_; p.sA2 = 256;
        p.Bt = Kb; p.ldb = L_; p.sB1 = (long)C_ * L_; p.sB2 = 256;
        p.outB = Sbf; p.ldc = 256; p.sC1 = (long)H_ * 65536; p.sC2 = 65536;
        gemm_bt<E_BF16><<<gAttn, blk, 0, stream>>>(p);
    }
    // ---- softmax -> P (into RP; rank is dead) ----
    softmax_kernel<<<dim3(160 * 256 / 4), blk, 0, stream>>>(Sbf, RP);
    // ---- O = P V  (into Qb; q is dead) ----
    {
        GemmP p{}; p.zmod = H_; p.K = 256;
        p.A = RP;  p.lda = 256; p.sA1 = (long)H_ * 65536; p.sA2 = 65536;
        p.Bt = VT; p.ldb = 256; p.sB1 = (long)H_ * 65536; p.sB2 = 65536;
        p.outB = Qb; p.ldc = L_; p.sC1 = (long)C_ * L_; p.sC2 = 256;
        gemm_bt<E_BF16><<<gAttn, blk, 0, stream>>>(p);
    }
    // ---- h = bf16(node + O @ wo + bo)  (in place over nodeB) ----
    {
        GemmP p{}; p.zmod = 1; p.K = L_;
        p.A = Qb; p.lda = L_; p.Bt = Wt[4]; p.ldb = L_;
        p.outB = nodeB; p.ldc = L_; p.bias = bo; p.resB = nodeB; p.ldres = L_;
        gemm_bt<E_HRES><<<gBig, blk, 0, stream>>>(p);
    }
    // ---- LN2 -> y2 (RP; P is dead) ----
    ln_kernel<<<dim3(BC_), blk, 0, stream>>>(nodeB, ln2g, ln2b, RP);
    // ---- f1 = gelu(y2 @ w1 + b1) (Yb; y is dead) ----
    {
        GemmP p{}; p.zmod = 1; p.K = L_;
        p.A = RP; p.lda = L_; p.Bt = Wt[5]; p.ldb = L_;
        p.outB = Yb; p.ldc = L_; p.bias = fb1;
        gemm_bt<E_GELU><<<gBig, blk, 0, stream>>>(p);
    }
    // ---- h2 = h + f1 @ w2 + b2 -> transposed+padded (Kb; k is dead) ----
    zero_pads<<<dim3(64), blk, 0, stream>>>(Kb);
    {
        GemmP p{}; p.zmod = 1; p.K = L_;
        p.A = Yb; p.lda = L_; p.Bt = Wt[6]; p.ldb = L_;
        p.outB = Kb; p.bias = fb2; p.resB = nodeB; p.ldres = L_;
        gemm_bt<E_FFN2T><<<gBig, blk, 0, stream>>>(p);
    }
    // ---- conv: single fused K=768 GEMM + BN + ReLU ----
    {
        GemmP p{}; p.zmod = 1; p.K = 768;
        p.A = WconvT; p.lda = 768;                       // [co][t*256+ci]
        p.Bt = Kb; p.ldb = 256; p.sB1 = 1282 * 256;      // row lc reads h2T rows lc..lc+2
        p.outF = out; p.ldc = L_; p.sC1 = (long)C_ * L_;
        p.rowscale = bnscale; p.rowbias = bnbias;
        gemm_bt<E_CONVBNR><<<dim3(L_ / 128, 2, B_), blk, 0, stream>>>(p);
    }
}

// Round 14
// 518.072 us; speedup vs baseline: 1.3718x; 1.0044x over previous
//
#include <hip/hip_runtime.h>
#include <hip/hip_bf16.h>
#include <stdint.h>

// Problem constants
#define L_   1280
#define B_   32
#define C_   256
#define H_   5
#define D_   256
#define BC_  8192            // B_*C_
#define EPSV 1e-5f

typedef __attribute__((ext_vector_type(8))) short bf16x8;   // 8 bf16 (4 VGPRs)
typedef __attribute__((ext_vector_type(4))) float f32x4;    // 4 fp32 acc
typedef __hip_bfloat16 bf16;

__device__ __forceinline__ bf16 f2bf(float v) { return __float2bfloat16(v); }
__device__ __forceinline__ float bf2f(bf16 v) { return __bfloat162float(v); }

// async global->LDS, 16B per lane; LDS dest is wave-uniform base + lane*16
#define GLDS16(gptr, lptr)                                                        \
    __builtin_amdgcn_global_load_lds(                                             \
        (const __attribute__((address_space(1))) void*)(gptr),                    \
        (__attribute__((address_space(3))) void*)(lptr), 16, 0, 0)

// ---------------------------------------------------------------------------
// Weight prep: fp32 [K,N] -> bf16 [N,K] (transposed) for 7 LxL matrices
// ---------------------------------------------------------------------------
struct WtArgs { const float* src[7]; bf16* dst[7]; };

__global__ __launch_bounds__(256) void transpose7(WtArgs a) {
    const int mat = blockIdx.z;
    const float* src = a.src[mat];
    bf16* dst = a.dst[mat];
    __shared__ float tile[32][33];
    const int bx = blockIdx.x * 32;   // n base
    const int by = blockIdx.y * 32;   // k base
    const int tx = threadIdx.x, ty = threadIdx.y;
    #pragma unroll
    for (int r = ty; r < 32; r += 8)
        tile[r][tx] = src[(size_t)(by + r) * L_ + bx + tx];
    __syncthreads();
    #pragma unroll
    for (int r = ty; r < 32; r += 8)
        dst[(size_t)(bx + r) * L_ + by + tx] = f2bf(tile[tx][r]);
}

// conv weight pack: conv_w[co][ci][t] -> WT[co][t*256+ci]  (K=768 fused layout)
// plus BN scale/bias
__global__ __launch_bounds__(256) void prep_conv(const float* cw, const float* g, const float* b,
                                                 const float* m, const float* v,
                                                 bf16* WT, float* sc, float* bi) {
    const int i = blockIdx.x * 256 + threadIdx.x;
    if (i < 3 * 256 * 256) {
        const int co = i / 768;
        const int r = i - co * 768;
        const int t = r >> 8, ci = r & 255;
        WT[i] = f2bf(cw[(co * 256 + ci) * 3 + t]);
    }
    if (i < 256) {
        const float s = g[i] * rsqrtf(v[i] + EPSV);
        sc[i] = s;
        bi[i] = b[i] - m[i] * s;
    }
}

// ---------------------------------------------------------------------------
// Rank kernel (bucket-histogram; eq-before term dropped, < 2e-5 effect)
// ---------------------------------------------------------------------------
__global__ __launch_bounds__(256) void rank_kernel(const float* __restrict__ x, bf16* __restrict__ R) {
    __shared__ float vals[L_];
    __shared__ float sv[L_];
    __shared__ int hist[256];
    __shared__ int pfx[256];
    __shared__ int cur[256];
    const int row = blockIdx.x, tid = threadIdx.x;
    const float* src = x + (size_t)row * L_;
    for (int i = tid; i < L_; i += 256) vals[i] = src[i];
    hist[tid] = 0;
    __syncthreads();
    float myv[5]; int myb[5];
    #pragma unroll
    for (int ii = 0; ii < 5; ii++) {
        const float v = vals[tid + ii * 256];
        int bk = (int)((4.0f - v) * 32.0f);
        bk = bk < 0 ? 0 : (bk > 255 ? 255 : bk);
        myv[ii] = v; myb[ii] = bk;
        atomicAdd(&hist[bk], 1);
    }
    __syncthreads();
    pfx[tid] = hist[tid];
    __syncthreads();
    for (int off = 1; off < 256; off <<= 1) {
        int t = (tid >= off) ? pfx[tid - off] : 0;
        __syncthreads();
        pfx[tid] += t;
        __syncthreads();
    }
    cur[tid] = pfx[tid] - hist[tid];
    __syncthreads();
    #pragma unroll
    for (int ii = 0; ii < 5; ii++) {
        const int pos = atomicAdd(&cur[myb[ii]], 1);
        sv[pos] = myv[ii];
    }
    __syncthreads();
    #pragma unroll
    for (int ii = 0; ii < 5; ii++) {
        const int bk = myb[ii]; const float v = myv[ii];
        const int s = pfx[bk] - hist[bk], e = pfx[bk];
        int cg = s;
        for (int p = s; p < e; p++) cg += (sv[p] > v) ? 1 : 0;
        R[(size_t)row * L_ + tid + ii * 256] = f2bf((float)(L_ - cg) * (1.0f / L_));
    }
}

// ---------------------------------------------------------------------------
// LayerNorm over last dim (1280), bf16 in -> bf16 out
// ---------------------------------------------------------------------------
__global__ __launch_bounds__(256) void ln_kernel(const bf16* __restrict__ in,
                                                 const float* __restrict__ g,
                                                 const float* __restrict__ b,
                                                 bf16* __restrict__ out) {
    const int row = blockIdx.x, tid = threadIdx.x;
    const bf16* src = in + (size_t)row * L_;
    uint2 ra = ((const uint2*)src)[tid];
    bf16 a4[4]; *(uint2*)a4 = ra;
    const float a0 = bf2f(a4[0]), a1 = bf2f(a4[1]), a2 = bf2f(a4[2]), a3 = bf2f(a4[3]);
    float s = a0 + a1 + a2 + a3;
    float ss = a0 * a0 + a1 * a1 + a2 * a2 + a3 * a3;
    float b0 = 0, b1 = 0, b2 = 0, b3 = 0;
    if (tid < 64) {
        uint2 rb = ((const uint2*)src)[256 + tid];
        bf16 b4[4]; *(uint2*)b4 = rb;
        b0 = bf2f(b4[0]); b1 = bf2f(b4[1]); b2 = bf2f(b4[2]); b3 = bf2f(b4[3]);
        s += b0 + b1 + b2 + b3;
        ss += b0 * b0 + b1 * b1 + b2 * b2 + b3 * b3;
    }
    #pragma unroll
    for (int off = 32; off > 0; off >>= 1) {
        s += __shfl_down(s, off, 64);
        ss += __shfl_down(ss, off, 64);
    }
    __shared__ float rs[4], rss[4];
    __shared__ float mean_s, rstd_s;
    if ((tid & 63) == 0) { rs[tid >> 6] = s; rss[tid >> 6] = ss; }
    __syncthreads();
    if (tid == 0) {
        const float S = rs[0] + rs[1] + rs[2] + rs[3];
        const float SS = rss[0] + rss[1] + rss[2] + rss[3];
        const float m = S * (1.0f / L_);
        const float var = SS * (1.0f / L_) - m * m;
        mean_s = m; rstd_s = rsqrtf(var + EPSV);
    }
    __syncthreads();
    const float m = mean_s, r = rstd_s;
    {
        const int c = tid * 4;
        bf16 t4[4];
        t4[0] = f2bf((a0 - m) * r * g[c + 0] + b[c + 0]);
        t4[1] = f2bf((a1 - m) * r * g[c + 1] + b[c + 1]);
        t4[2] = f2bf((a2 - m) * r * g[c + 2] + b[c + 2]);
        t4[3] = f2bf((a3 - m) * r * g[c + 3] + b[c + 3]);
        *(uint2*)(out + (size_t)row * L_ + c) = *(uint2*)t4;
    }
    if (tid < 64) {
        const int c = 1024 + tid * 4;
        bf16 t4[4];
        t4[0] = f2bf((b0 - m) * r * g[c + 0] + b[c + 0]);
        t4[1] = f2bf((b1 - m) * r * g[c + 1] + b[c + 1]);
        t4[2] = f2bf((b2 - m) * r * g[c + 2] + b[c + 2]);
        t4[3] = f2bf((b3 - m) * r * g[c + 3] + b[c + 3]);
        *(uint2*)(out + (size_t)row * L_ + c) = *(uint2*)t4;
    }
}

// ---------------------------------------------------------------------------
// Row softmax: 256 bf16 logits -> 256 bf16 probs, one wave per row
// ---------------------------------------------------------------------------
__global__ __launch_bounds__(256) void softmax_kernel(const bf16* __restrict__ S, bf16* __restrict__ P) {
    const int row = blockIdx.x * 4 + (threadIdx.x >> 6);
    const int l = threadIdx.x & 63;
    const bf16* src = S + (size_t)row * 256 + l * 4;
    uint2 raw = *(const uint2*)src;
    bf16 s4[4]; *(uint2*)s4 = raw;
    float v0 = bf2f(s4[0]), v1 = bf2f(s4[1]);
    float v2 = bf2f(s4[2]), v3 = bf2f(s4[3]);
    float mx = fmaxf(fmaxf(v0, v1), fmaxf(v2, v3));
    #pragma unroll
    for (int off = 1; off < 64; off <<= 1) mx = fmaxf(mx, __shfl_xor(mx, off, 64));
    const float e0 = expf(v0 - mx), e1 = expf(v1 - mx), e2 = expf(v2 - mx), e3 = expf(v3 - mx);
    float sm = e0 + e1 + e2 + e3;
    #pragma unroll
    for (int off = 1; off < 64; off <<= 1) sm += __shfl_xor(sm, off, 64);
    const float inv = 1.0f / sm;
    bf16 t4[4] = { f2bf(e0 * inv), f2bf(e1 * inv), f2bf(e2 * inv), f2bf(e3 * inv) };
    *(uint2*)(P + (size_t)row * 256 + l * 4) = *(uint2*)t4;
}

// zero the two pad rows of h2Tpad [B][1282][256]
__global__ __launch_bounds__(256) void zero_pads(bf16* h2T) {
    const int i = blockIdx.x * 256 + threadIdx.x;   // 32*2*256 = 16384
    const int b = i >> 9;
    const int which = (i >> 8) & 1;
    const int ci = i & 255;
    const long row = which ? 1281 : 0;
    h2T[(long)b * (1282 * 256) + row * 256 + ci] = f2bf(0.0f);
}

// ---------------------------------------------------------------------------
// Generic batched GEMM: C[z][m][n] = sum_k A[z][m][k] * Bt[z][n][k]
// 128x128 tile, BK=32, 4 waves, mfma_f32_16x16x32_bf16.
// 3-buffer rotation, ONE barrier + counted vmcnt(4) per K-step (T3/T4).
// XOR chunk-swizzle (T2, rule#21): linear LDS dest, per-lane-swizzled global
// SOURCE chunk ((l&3)^((l>>2)&3)), matching XOR on the ds_read side
// ((l>>4)^(row&3), row&3==l&3) -> 2 lanes/bank, conflict-free.
// XCD chunking with row-fastest order inside each chunk (B-tile L2 reuse).
// V-output blocks route the store through an LDS transpose (coalesced Vt).
// ---------------------------------------------------------------------------
struct GemmP {
    const bf16* A;  long lda, sA1, sA2;
    const bf16* Bt; long ldb, sB1, sB2;
    int zmod;
    int K;
    float* outF; bf16* outB; bf16* outB2; bf16* outB3; long ldc, sC1, sC2;
    const float* bias; const float* bias2; const float* bias3;
    const float* res; const bf16* resB; long ldres, sR1, sR2;
    const float* rowscale; const float* rowbias;
    float scale;
};

constexpr int E_NODE = 0;          // outB = bf16(acc + bias + resF32)    (node = x + ...)
constexpr int E_HRES = 1;          // outB = bf16(acc + bias + f(resB))   (h, in-place)
constexpr int E_BF16 = 5;          // outB = bf16(acc) (with z offset)
constexpr int E_GELU = 6;          // outB = bf16(gelu(acc+bias))
constexpr int E_FFN2T = 7;         // h2 transposed+padded store (bf16 res)
constexpr int E_CONVBNR = 8;       // relu(acc*rowscale+rowbias) -> outF
constexpr int E_QKV = 9;           // col<1280: Q*scale; <2560: K; else V via LDS-transpose

template <int EPI>
__global__ __launch_bounds__(256) void gemm_bt(GemmP p) {
    // ---- XCD chunking; row-fastest order within chunk ----
    const int nwg  = gridDim.x * gridDim.y * gridDim.z;
    const int orig = (blockIdx.z * gridDim.y + blockIdx.y) * gridDim.x + blockIdx.x;
    int bx, rowg;
    if ((nwg & 7) == 0) {
        const int chunk = nwg >> 3;
        const int xcd = orig & 7, pos = orig >> 3;
        const int rpc = chunk / gridDim.x;           // rows per chunk
        if (rpc * gridDim.x == chunk) {
            bx   = pos / rpc;                        // B-tile shared by rpc row-blocks
            rowg = xcd * rpc + (pos - bx * rpc);     // A-chunk stays L2-resident
        } else {
            const int wgid = xcd * chunk + pos;
            bx = wgid % gridDim.x; rowg = wgid / gridDim.x;
        }
    } else {
        bx = blockIdx.x; rowg = blockIdx.z * gridDim.y + blockIdx.y;
    }
    const int by = rowg % gridDim.y;
    const int bz = rowg / gridDim.y;

    const int zq = bz / p.zmod, zr = bz % p.zmod;
    const bf16* A  = p.A  + (long)zq * p.sA1 + (long)zr * p.sA2;
    const bf16* Bt = p.Bt + (long)zq * p.sB1 + (long)zr * p.sB2;
    const int row0 = by * 128, col0 = bx * 128;

    // 48 KB LDS: 3 x (A 8K + B 8K); reused whole as 128x128 bf16 transpose
    // scratch in the V epilogue.
    __shared__ __align__(16) bf16 shm[24576];

    const int tid = threadIdx.x;
    const int l = tid & 63, w = tid >> 6;
    const int wr = w >> 1, wc = w & 1;

    f32x4 acc[4][4];
    #pragma unroll
    for (int m = 0; m < 4; m++)
        #pragma unroll
        for (int n = 0; n < 4; n++)
            acc[m][n] = (f32x4){0.f, 0.f, 0.f, 0.f};

    // per-lane SOURCE chunk swizzle (involution): chunk' = (l&3) ^ (row&3)
    const int srcChunk = (l & 3) ^ ((l >> 2) & 3);
    const bf16* gA = A  + (long)(row0 + w * 16 + (l >> 2)) * p.lda + srcChunk * 8;
    const bf16* gB = Bt + (long)(col0 + w * 16 + (l >> 2)) * p.ldb + srcChunk * 8;
    const long aStep = 64 * p.lda, bStep = 64 * p.ldb;

    auto STAGE = [&](int buf) {
        bf16* lA = shm + buf * 4096;
        bf16* lB = shm + 12288 + buf * 4096;
        GLDS16(gA,         lA + w * 512);
        GLDS16(gA + aStep, lA + 2048 + w * 512);
        GLDS16(gB,         lB + w * 512);
        GLDS16(gB + bStep, lB + 2048 + w * 512);
        gA += 32; gB += 32;
    };
    // matching READ swizzle: chunk position = (l>>4) ^ (row&3); row&3 == l&3
    const int rdOff = (((l >> 4) ^ (l & 3)) * 8);
    auto COMPUTE = [&](int buf) {
        const bf16* lA = shm + buf * 4096;
        const bf16* lB = shm + 12288 + buf * 4096;
        bf16x8 aF[4], bF[4];
        #pragma unroll
        for (int m = 0; m < 4; m++)
            aF[m] = *(const bf16x8*)(lA + (wr * 64 + m * 16 + (l & 15)) * 32 + rdOff);
        #pragma unroll
        for (int n = 0; n < 4; n++)
            bF[n] = *(const bf16x8*)(lB + (wc * 64 + n * 16 + (l & 15)) * 32 + rdOff);
        #pragma unroll
        for (int m = 0; m < 4; m++)
            #pragma unroll
            for (int n = 0; n < 4; n++)
                acc[m][n] = __builtin_amdgcn_mfma_f32_16x16x32_bf16(aF[m], bF[n], acc[m][n], 0, 0, 0);
    };

    // ---- 3-buffer rotation: 1 barrier + counted vmcnt per K-step ----
    const int nt = p.K >> 5;          // nt >= 8 for all our shapes
    STAGE(0); STAGE(1);               // tiles 0,1 in flight (8 loads/wave)
    int cb = 0, sb = 2;
    for (int t = 0; t < nt - 1; ++t) {
        asm volatile("s_waitcnt vmcnt(4)" ::: "memory");   // retire tile t only
        __builtin_amdgcn_sched_barrier(0);
        __builtin_amdgcn_s_barrier();                      // buf[cb] ready; buf[sb] free
        if (t + 2 < nt) STAGE(sb);                         // tile t+2 in flight
        COMPUTE(cb);
        cb = (cb == 2) ? 0 : cb + 1;
        sb = (sb == 2) ? 0 : sb + 1;
    }
    asm volatile("s_waitcnt vmcnt(0)" ::: "memory");
    __builtin_amdgcn_sched_barrier(0);
    __builtin_amdgcn_s_barrier();
    COMPUTE(cb);                                           // last tile

    // ---- V-block epilogue: LDS transpose -> coalesced 16B stores ----
    if constexpr (EPI == E_QKV) {
        if (col0 >= 2560) {
            const int v0  = col0 - 2560;
            const int hh  = v0 >> 8;
            const int dd0 = v0 & 255;          // 0 or 128
            const int b_  = row0 >> 8;
            const int c0b = row0 & 255;        // 0 or 128
            __syncthreads();                   // pipeline LDS reads done; reuse shm
            #pragma unroll
            for (int m = 0; m < 4; m++)
                #pragma unroll
                for (int n = 0; n < 4; n++) {
                    const int cc = wc * 64 + n * 16 + (l & 15);   // local d
                    const float bb = p.bias3[v0 + cc];
                    #pragma unroll
                    for (int j = 0; j < 4; j++) {
                        const int r = wr * 64 + m * 16 + (l >> 4) * 4 + j;  // local c
                        shm[cc * 128 + (r ^ ((cc & 7) << 3))] = f2bf(acc[m][n][j] + bb);
                    }
                }
            __syncthreads();
            const int d = tid >> 1, ch = (tid & 1) * 64;
            bf16* dstRow = p.outB3 +
                (((long)((b_ * H_ + hh) * 256 + dd0 + d)) << 8) + c0b;
            #pragma unroll
            for (int g = 0; g < 8; g++) {
                const int rb = ch + g * 8;
                *(bf16x8*)(dstRow + rb) =
                    *(const bf16x8*)&shm[d * 128 + (rb ^ ((d & 7) << 3))];
            }
            return;
        }
    }

    const long cz = (long)zq * p.sC1 + (long)zr * p.sC2;
    const long rz = (long)zq * p.sR1 + (long)zr * p.sR2;
    #pragma unroll
    for (int m = 0; m < 4; m++) {
        #pragma unroll
        for (int n = 0; n < 4; n++) {
            const int gcol = col0 + wc * 64 + n * 16 + (l & 15);
            #pragma unroll
            for (int j = 0; j < 4; j++) {
                const int grow = row0 + wr * 64 + m * 16 + (l >> 4) * 4 + j;
                const float v = acc[m][n][j];
                if constexpr (EPI == E_NODE) {
                    p.outB[cz + (long)grow * p.ldc + gcol] =
                        f2bf(v + p.bias[gcol] + p.res[rz + (long)grow * p.ldres + gcol]);
                } else if constexpr (EPI == E_HRES) {
                    p.outB[cz + (long)grow * p.ldc + gcol] =
                        f2bf(v + p.bias[gcol] + bf2f(p.resB[rz + (long)grow * p.ldres + gcol]));
                } else if constexpr (EPI == E_BF16) {
                    p.outB[cz + (long)grow * p.ldc + gcol] = f2bf(v);
                } else if constexpr (EPI == E_GELU) {
                    const float t = v + p.bias[gcol];
                    p.outB[cz + (long)grow * p.ldc + gcol] =
                        f2bf(0.5f * t * (1.0f + erff(t * 0.70710678f)));
                } else if constexpr (EPI == E_FFN2T) {
                    const float t = v + p.bias[gcol] +
                                    bf2f(p.resB[rz + (long)grow * p.ldres + gcol]);
                    const int b_ = grow >> 8, ci = grow & 255;
                    p.outB[(long)b_ * (1282 * 256) + (long)(gcol + 1) * 256 + ci] = f2bf(t);
                } else if constexpr (EPI == E_CONVBNR) {
                    const float t = v * p.rowscale[grow] + p.rowbias[grow];
                    p.outF[cz + (long)grow * p.ldc + gcol] = fmaxf(t, 0.0f);
                } else if constexpr (EPI == E_QKV) {
                    if (gcol < 1280) {                       // Q (scaled)
                        p.outB[(long)grow * L_ + gcol] = f2bf((v + p.bias[gcol]) * p.scale);
                    } else {                                 // K
                        const int c2 = gcol - 1280;
                        p.outB2[(long)grow * L_ + c2] = f2bf(v + p.bias2[c2]);
                    }
                }
            }
        }
    }
}

// ---------------------------------------------------------------------------
extern "C" void kernel_launch(void* const* d_in, const int* in_sizes, int n_in,
                              void* d_out, int out_size, void* d_ws, size_t ws_size,
                              hipStream_t stream) {
    const float* x    = (const float*)d_in[0];
    const float* re_w = (const float*)d_in[1];
    const float* re_b = (const float*)d_in[2];
    const float* ln1g = (const float*)d_in[3];
    const float* ln1b = (const float*)d_in[4];
    const float* ln2g = (const float*)d_in[5];
    const float* ln2b = (const float*)d_in[6];
    const float* wq   = (const float*)d_in[7];
    const float* bq   = (const float*)d_in[8];
    const float* wk   = (const float*)d_in[9];
    const float* bk   = (const float*)d_in[10];
    const float* wv   = (const float*)d_in[11];
    const float* bv   = (const float*)d_in[12];
    const float* wo   = (const float*)d_in[13];
    const float* bo   = (const float*)d_in[14];
    const float* fw1  = (const float*)d_in[15];
    const float* fb1  = (const float*)d_in[16];
    const float* fw2  = (const float*)d_in[17];
    const float* fb2  = (const float*)d_in[18];
    const float* convw = (const float*)d_in[19];
    const float* bng  = (const float*)d_in[20];
    const float* bnb  = (const float*)d_in[21];
    const float* bnm  = (const float*)d_in[22];
    const float* bnv  = (const float*)d_in[23];
    float* out = (float*)d_out;

    // ---- workspace layout (total ~170 MB) ----
    char* ws = (char*)d_ws;
    const size_t SZ_WT     = (size_t)L_ * L_ * 2;          // 3,276,800
    const size_t SZ_ACT_BF = (size_t)BC_ * L_ * 2;         // 20,971,520
    const size_t SZ_H2T    = (size_t)B_ * 1282 * 256 * 2;  // 21,004,288
    const size_t SZ_S      = (size_t)160 * 256 * 256 * 4;  // 41,943,040

    size_t off = 0;
    bf16* Wt[7];
    for (int i = 0; i < 7; i++) { Wt[i] = (bf16*)(ws + off); off += SZ_WT; }  // contiguous!
    bf16* WconvT   = (bf16*)(ws + off); off += 393216;
    float* bnscale = (float*)(ws + off); off += 1024;
    float* bnbias  = (float*)(ws + off); off += 1024;
    bf16* RP  = (bf16*)(ws + off); off += SZ_ACT_BF;  // rank -> P -> y2
    bf16* Yb  = (bf16*)(ws + off); off += SZ_ACT_BF;  // y -> f1
    bf16* Qb  = (bf16*)(ws + off); off += SZ_ACT_BF;  // q -> attn O
    bf16* Kb  = (bf16*)(ws + off); off += SZ_H2T;     // k -> h2Tpad
    float* Sb = (float*)(ws + off); off += SZ_S;      // [Sbf16 21MB][VT 21MB]
    bf16* nodeB = (bf16*)(ws + off); off += SZ_ACT_BF; // node -> h (bf16, in place)
    bf16* Sbf = (bf16*)Sb;                             // bf16 scores, first half
    bf16* VT  = Sbf + (size_t)160 * 65536;             // V^T, second half
    (void)in_sizes; (void)n_in; (void)out_size;

    // Diagnostic guard: if ws is too small, fail cleanly (absmax ~8.5, no fault)
    if (ws_size < off) return;

    // ---- weight prep ----
    WtArgs wa;
    wa.src[0] = re_w; wa.src[1] = wq; wa.src[2] = wk; wa.src[3] = wv;
    wa.src[4] = wo;  wa.src[5] = fw1; wa.src[6] = fw2;
    for (int i = 0; i < 7; i++) wa.dst[i] = Wt[i];
    transpose7<<<dim3(40, 40, 7), dim3(32, 8), 0, stream>>>(wa);
    prep_conv<<<dim3(768), 256, 0, stream>>>(convw, bng, bnb, bnm, bnv, WconvT, bnscale, bnbias);

    // ---- rank ----
    rank_kernel<<<dim3(BC_), 256, 0, stream>>>(x, RP);

    const dim3 gBig(L_ / 128, BC_ / 128, 1);      // (10, 64)
    const dim3 gQKV(3840 / 128, BC_ / 128, 1);    // (30, 64)
    const dim3 gAttn(2, 2, 160);
    const dim3 blk(256);

    // ---- node = bf16(x + rank @ re_w + re_b) ----
    {
        GemmP p{}; p.zmod = 1; p.K = L_;
        p.A = RP; p.lda = L_; p.Bt = Wt[0]; p.ldb = L_;
        p.outB = nodeB; p.ldc = L_; p.bias = re_b; p.res = x; p.ldres = L_;
        gemm_bt<E_NODE><<<gBig, blk, 0, stream>>>(p);
    }
    // ---- LN1 -> y ----
    ln_kernel<<<dim3(BC_), blk, 0, stream>>>(nodeB, ln1g, ln1b, Yb);
    // ---- Q (scaled) + K + V(transposed) fused: Bt = Wt[1]||Wt[2]||Wt[3] ----
    {
        GemmP p{}; p.zmod = 1; p.K = L_;
        p.A = Yb; p.lda = L_; p.Bt = Wt[1]; p.ldb = L_;
        p.outB = Qb; p.outB2 = Kb; p.outB3 = VT;
        p.bias = bq; p.bias2 = bk; p.bias3 = bv; p.scale = 0.0625f;
        gemm_bt<E_QKV><<<gQKV, blk, 0, stream>>>(p);
    }
    // ---- S = q k^T per (b,h), bf16 logits ----
    {
        GemmP p{}; p.zmod = H_; p.K = 256;
        p.A = Qb;  p.lda = L_; p.sA1 = (long)C_ * L_; p.sA2 = 256;
        p.Bt = Kb; p.ldb = L_; p.sB1 = (long)C_ * L_; p.sB2 = 256;
        p.outB = Sbf; p.ldc = 256; p.sC1 = (long)H_ * 65536; p.sC2 = 65536;
        gemm_bt<E_BF16><<<gAttn, blk, 0, stream>>>(p);
    }
    // ---- softmax -> P (into RP; rank is dead) ----
    softmax_kernel<<<dim3(160 * 256 / 4), blk, 0, stream>>>(Sbf, RP);
    // ---- O = P V  (into Qb; q is dead) ----
    {
        GemmP p{}; p.zmod = H_; p.K = 256;
        p.A = RP;  p.lda = 256; p.sA1 = (long)H_ * 65536; p.sA2 = 65536;
        p.Bt = VT; p.ldb = 256; p.sB1 = (long)H_ * 65536; p.sB2 = 65536;
        p.outB = Qb; p.ldc = L_; p.sC1 = (long)C_ * L_; p.sC2 = 256;
        gemm_bt<E_BF16><<<gAttn, blk, 0, stream>>>(p);
    }
    // ---- h = bf16(node + O @ wo + bo)  (in place over nodeB) ----
    {
        GemmP p{}; p.zmod = 1; p.K = L_;
        p.A = Qb; p.lda = L_; p.Bt = Wt[4]; p.ldb = L_;
        p.outB = nodeB; p.ldc = L_; p.bias = bo; p.resB = nodeB; p.ldres = L_;
        gemm_bt<E_HRES><<<gBig, blk, 0, stream>>>(p);
    }
    // ---- LN2 -> y2 (RP; P is dead) ----
    ln_kernel<<<dim3(BC_), blk, 0, stream>>>(nodeB, ln2g, ln2b, RP);
    // ---- f1 = gelu(y2 @ w1 + b1) (Yb; y is dead) ----
    {
        GemmP p{}; p.zmod = 1; p.K = L_;
        p.A = RP; p.lda = L_; p.Bt = Wt[5]; p.ldb = L_;
        p.outB = Yb; p.ldc = L_; p.bias = fb1;
        gemm_bt<E_GELU><<<gBig, blk, 0, stream>>>(p);
    }
    // ---- h2 = h + f1 @ w2 + b2 -> transposed+padded (Kb; k is dead) ----
    zero_pads<<<dim3(64), blk, 0, stream>>>(Kb);
    {
        GemmP p{}; p.zmod = 1; p.K = L_;
        p.A = Yb; p.lda = L_; p.Bt = Wt[6]; p.ldb = L_;
        p.outB = Kb; p.bias = fb2; p.resB = nodeB; p.ldres = L_;
        gemm_bt<E_FFN2T><<<gBig, blk, 0, stream>>>(p);
    }
    // ---- conv: single fused K=768 GEMM + BN + ReLU ----
    {
        GemmP p{}; p.zmod = 1; p.K = 768;
        p.A = WconvT; p.lda = 768;                       // [co][t*256+ci]
        p.Bt = Kb; p.ldb = 256; p.sB1 = 1282 * 256;      // row lc reads h2T rows lc..lc+2
        p.outF = out; p.ldc = L_; p.sC1 = (long)C_ * L_;
        p.rowscale = bnscale; p.rowbias = bnbias;
        gemm_bt<E_CONVBNR><<<dim3(L_ / 128, 2, B_), blk, 0, stream>>>(p);
    }
}